// Round 12
// baseline (180.057 us; speedup 1.0000x reference)
//
#include <hip/hip_runtime.h>
#include <cstdint>
#include <cstddef>

#define B_ 32
#define T_ 1024
#define S_ 512
#define C_ 384
#define HALF_LOG_2PI 0.91893853320467274178f
#define LN2F 0.69314718055994530942f
#define INV_LN2F 1.44269504088896340736f

typedef unsigned short u16;
typedef unsigned long long u64;
typedef __attribute__((ext_vector_type(8))) short bf16x8;
typedef __attribute__((ext_vector_type(4))) float f32x4;

__device__ __forceinline__ unsigned rne16(float f) {   // f32 -> bf16 bits (RNE)
    unsigned b = __float_as_uint(f);
    return (b + 0x7FFFu + ((b >> 16) & 1u)) >> 16;
}
__device__ __forceinline__ uint4 cvt8(float4 lo, float4 hi) {  // 8 f32 -> 8 bf16
    uint4 q;
    asm("v_cvt_pk_bf16_f32 %0, %1, %2" : "=v"(q.x) : "v"(lo.x), "v"(lo.y));
    asm("v_cvt_pk_bf16_f32 %0, %1, %2" : "=v"(q.y) : "v"(lo.z), "v"(lo.w));
    asm("v_cvt_pk_bf16_f32 %0, %1, %2" : "=v"(q.z) : "v"(hi.x), "v"(hi.y));
    asm("v_cvt_pk_bf16_f32 %0, %1, %2" : "=v"(q.w) : "v"(hi.z), "v"(hi.w));
    return q;
}
__device__ __forceinline__ uint4 pack8f(float a0, float a1, float a2, float a3,
                                        float a4, float a5, float a6, float a7) {
    uint4 q;
    q.x = rne16(a0) | (rne16(a1) << 16);
    q.y = rne16(a2) | (rne16(a3) << 16);
    q.z = rne16(a4) | (rne16(a5) << 16);
    q.w = rne16(a6) | (rne16(a7) << 16);
    return q;
}
#define UNPK(q, p)                                                              \
    float p##0 = __uint_as_float((q).x << 16),                                  \
          p##1 = __uint_as_float((q).x & 0xFFFF0000u),                          \
          p##2 = __uint_as_float((q).y << 16),                                  \
          p##3 = __uint_as_float((q).y & 0xFFFF0000u),                          \
          p##4 = __uint_as_float((q).z << 16),                                  \
          p##5 = __uint_as_float((q).z & 0xFFFF0000u),                          \
          p##6 = __uint_as_float((q).w << 16),                                  \
          p##7 = __uint_as_float((q).w & 0xFFFF0000u)

#define PROW(t) (*(const uint4*)(Pb  + (size_t)(t) * S_ + l8))
#define BROW(t) (*(const uint4*)(Btb + (size_t)(t) * S_ + l8))

// ---------------------------------------------------------------------------
// DPP helpers: VALU-only cross-lane.
template <int CTRL>
__device__ __forceinline__ float fdpp0(float x) {     // invalid src lanes -> 0
    return __uint_as_float((unsigned)__builtin_amdgcn_update_dpp(
        0, (int)__float_as_uint(x), CTRL, 0xF, 0xF, true));
}
__device__ __forceinline__ float wave_fmax(float x) { // uniform full-wave max
    x = fmaxf(x, fdpp0<0x121>(x));   // row_ror:1
    x = fmaxf(x, fdpp0<0x122>(x));   // row_ror:2
    x = fmaxf(x, fdpp0<0x124>(x));   // row_ror:4
    x = fmaxf(x, fdpp0<0x128>(x));   // row_ror:8
    float a = __uint_as_float((unsigned)__builtin_amdgcn_readlane((int)__float_as_uint(x), 0));
    float b = __uint_as_float((unsigned)__builtin_amdgcn_readlane((int)__float_as_uint(x), 16));
    float c = __uint_as_float((unsigned)__builtin_amdgcn_readlane((int)__float_as_uint(x), 32));
    float d = __uint_as_float((unsigned)__builtin_amdgcn_readlane((int)__float_as_uint(x), 48));
    return fmaxf(fmaxf(a, b), fmaxf(c, d));
}

__device__ __forceinline__ void gll16(const u16* g, u16* l) {
    __builtin_amdgcn_global_load_lds(
        (const __attribute__((address_space(1))) void*)g,
        (__attribute__((address_space(3))) void*)l, 16, 0, 0);
}
#define WAITV(N) do { asm volatile("s_waitcnt vmcnt(" #N ")" ::: "memory");     \
                      __builtin_amdgcn_sched_barrier(0); } while (0)
#define FENCE_LGKM() do { asm volatile("s_waitcnt lgkmcnt(0)" ::: "memory");    \
                          __builtin_amdgcn_sched_barrier(0); } while (0)

// ---------------------------------------------------------------------------
// K0: masked -0.5*sum(eps^2) partials (read-only; bf16 conversion now in gemm).
__global__ __launch_bounds__(256) void k_eps(const float* __restrict__ eps,
                                             const int* __restrict__ tlen,
                                             float* __restrict__ lp_part) {
    const int b = blockIdx.x / 48, chunk = blockIdx.x % 48;
    const int len = tlen[b];
    const float* base = eps + (size_t)b * T_ * C_ + (size_t)chunk * 8192;
    float acc = 0.f;
    for (int g = threadIdx.x; g < 1024; g += 256) {
        float4 v0 = *(const float4*)(base + g * 8);
        float4 v1 = *(const float4*)(base + g * 8 + 4);
        int t = (chunk * 8192 + g * 8) / C_;
        if (t < len)
            acc += v0.x*v0.x + v0.y*v0.y + v0.z*v0.z + v0.w*v0.w
                 + v1.x*v1.x + v1.y*v1.y + v1.z*v1.z + v1.w*v1.w;
    }
    __shared__ float red[256];
    red[threadIdx.x] = acc;
    __syncthreads();
    for (int o = 128; o > 0; o >>= 1) {
        if (threadIdx.x < o) red[threadIdx.x] += red[threadIdx.x + o];
        __syncthreads();
    }
    if (threadIdx.x == 0) lp_part[blockIdx.x] = -0.5f * red[0];
}

// ---------------------------------------------------------------------------
// K1: bf16 MFMA GEMM from f32 inputs (convert during LDS staging).
// 128x128 tile, 4 waves, BK=32 -> bf16 logits Wb.
__global__ __launch_bounds__(256) void k_gemm(const float* __restrict__ A,
                                              const float* __restrict__ Bc,
                                              u16* __restrict__ Wb) {
    __shared__ u16 Al[4096];
    __shared__ u16 Bl[4096];
    const int b  = blockIdx.z;
    const int m0 = blockIdx.y * 128;
    const int n0 = blockIdx.x * 128;
    const int tid = threadIdx.x;
    const int lane = tid & 63, wid = tid >> 6;
    const int wy = wid >> 1, wx = wid & 1;
    const int r15 = lane & 15, kg = lane >> 4;
    const float* Ab = A  + (size_t)b * T_ * C_;
    const float* Bb = Bc + (size_t)b * S_ * C_;

    f32x4 acc[4][4];
#pragma unroll
    for (int i = 0; i < 4; ++i)
#pragma unroll
        for (int j = 0; j < 4; ++j) acc[i][j] = (f32x4){0.f, 0.f, 0.f, 0.f};

    const int row0 = tid >> 2, o0 = tid & 3;
    const int row1 = row0 + 64;
    const int wb0 = (row0 * 64 + o0 * 16) ^ (((row0 >> 1) & 7) << 4);
    const int wb1 = (row1 * 64 + o0 * 16) ^ (((row1 >> 1) & 7) << 4);
    const int rswz = ((r15 >> 1) & 7) << 4;

    for (int k0 = 0; k0 < C_; k0 += 32) {
        const float* pa0 = Ab + (size_t)(m0 + row0) * C_ + k0 + o0 * 8;
        const float* pa1 = Ab + (size_t)(m0 + row1) * C_ + k0 + o0 * 8;
        const float* pc0 = Bb + (size_t)(n0 + row0) * C_ + k0 + o0 * 8;
        const float* pc1 = Bb + (size_t)(n0 + row1) * C_ + k0 + o0 * 8;
        float4 aL0 = *(const float4*)pa0, aH0 = *(const float4*)(pa0 + 4);
        float4 aL1 = *(const float4*)pa1, aH1 = *(const float4*)(pa1 + 4);
        float4 cL0 = *(const float4*)pc0, cH0 = *(const float4*)(pc0 + 4);
        float4 cL1 = *(const float4*)pc1, cH1 = *(const float4*)(pc1 + 4);
        uint4 a0 = cvt8(aL0, aH0), a1 = cvt8(aL1, aH1);
        uint4 c0 = cvt8(cL0, cH0), c1 = cvt8(cL1, cH1);
        __syncthreads();
        *(uint4*)((char*)Al + wb0) = a0;
        *(uint4*)((char*)Al + wb1) = a1;
        *(uint4*)((char*)Bl + wb0) = c0;
        *(uint4*)((char*)Bl + wb1) = c1;
        __syncthreads();
        bf16x8 af[4], bfb[4];
#pragma unroll
        for (int ar = 0; ar < 4; ++ar) {
            int row = wy * 64 + ar * 16 + r15;
            af[ar] = *(const bf16x8*)((const char*)Al + ((row * 64 + kg * 16) ^ rswz));
        }
#pragma unroll
        for (int bc = 0; bc < 4; ++bc) {
            int row = wx * 64 + bc * 16 + r15;
            bfb[bc] = *(const bf16x8*)((const char*)Bl + ((row * 64 + kg * 16) ^ rswz));
        }
#pragma unroll
        for (int ar = 0; ar < 4; ++ar)
#pragma unroll
            for (int bc = 0; bc < 4; ++bc)
                acc[ar][bc] = __builtin_amdgcn_mfma_f32_16x16x32_bf16(
                    af[ar], bfb[bc], acc[ar][bc], 0, 0, 0);
    }
#pragma unroll
    for (int ar = 0; ar < 4; ++ar) {
        int t = m0 + wy * 64 + ar * 16 + kg * 4;
#pragma unroll
        for (int bc = 0; bc < 4; ++bc) {
            int s = n0 + wx * 64 + bc * 16 + r15;
            u16* dst = Wb + ((size_t)b * T_ + t) * S_ + s;
#pragma unroll
            for (int r = 0; r < 4; ++r) dst[(size_t)r * S_] = (u16)rne16(acc[ar][bc][r]);
        }
    }
}

// ---------------------------------------------------------------------------
// K2a: column stats over 256-row chunk. 4 waves, 8 cols/lane, uint4 row loads.
#define COLU(i, xa, xb, xc, xd) do {                                            \
    float nm = fmaxf(fmaxf(fmaxf(m[i], xa), xb), fmaxf(xc, xd));                \
    s[i] = s[i] * __builtin_amdgcn_exp2f((m[i] - nm) * INV_LN2F)                \
         + __builtin_amdgcn_exp2f((xa - nm) * INV_LN2F)                         \
         + __builtin_amdgcn_exp2f((xb - nm) * INV_LN2F)                         \
         + __builtin_amdgcn_exp2f((xc - nm) * INV_LN2F)                         \
         + __builtin_amdgcn_exp2f((xd - nm) * INV_LN2F);                        \
    m[i] = nm;                                                                  \
} while (0)

__global__ __launch_bounds__(256) void k_stats1(const u16* __restrict__ Wb,
                                                float* __restrict__ pmax,
                                                float* __restrict__ psum) {
    __shared__ float smax[4][S_];
    __shared__ float ssum[4][S_];
    const int c = blockIdx.x & 3;
    const int b = blockIdx.x >> 2;
    const int w = threadIdx.x >> 6, l = threadIdx.x & 63;
    const u16* base = Wb + (size_t)b * T_ * S_ + (size_t)(c * 256 + w * 64) * S_ + l * 8;
    float m[8], s[8];
#pragma unroll
    for (int i = 0; i < 8; ++i) { m[i] = -3.0e38f; s[i] = 0.f; }
    for (int t = 0; t < 64; t += 4) {
        uint4 q0 = *(const uint4*)(base + (size_t)(t + 0) * S_);
        uint4 q1 = *(const uint4*)(base + (size_t)(t + 1) * S_);
        uint4 q2 = *(const uint4*)(base + (size_t)(t + 2) * S_);
        uint4 q3 = *(const uint4*)(base + (size_t)(t + 3) * S_);
        UNPK(q0, xa); UNPK(q1, xb); UNPK(q2, xc); UNPK(q3, xd);
        COLU(0, xa0, xb0, xc0, xd0);
        COLU(1, xa1, xb1, xc1, xd1);
        COLU(2, xa2, xb2, xc2, xd2);
        COLU(3, xa3, xb3, xc3, xd3);
        COLU(4, xa4, xb4, xc4, xd4);
        COLU(5, xa5, xb5, xc5, xd5);
        COLU(6, xa6, xb6, xc6, xd6);
        COLU(7, xa7, xb7, xc7, xd7);
    }
#pragma unroll
    for (int i = 0; i < 8; ++i) {
        smax[w][l * 8 + i] = m[i];
        ssum[w][l * 8 + i] = s[i];
    }
    __syncthreads();
    for (int col = threadIdx.x; col < S_; col += 256) {
        float m0 = smax[0][col], m1 = smax[1][col];
        float m2 = smax[2][col], m3 = smax[3][col];
        float nm = fmaxf(fmaxf(m0, m1), fmaxf(m2, m3));
        float ss = ssum[0][col] * __builtin_amdgcn_exp2f((m0 - nm) * INV_LN2F)
                 + ssum[1][col] * __builtin_amdgcn_exp2f((m1 - nm) * INV_LN2F)
                 + ssum[2][col] * __builtin_amdgcn_exp2f((m2 - nm) * INV_LN2F)
                 + ssum[3][col] * __builtin_amdgcn_exp2f((m3 - nm) * INV_LN2F);
        pmax[(size_t)c * B_ * S_ + b * S_ + col] = nm;
        psum[(size_t)c * B_ * S_ + b * S_ + col] = ss;
    }
}

__global__ __launch_bounds__(256) void k_stats2(const float* __restrict__ pmax,
                                                const float* __restrict__ psum,
                                                float* __restrict__ cmax,
                                                float* __restrict__ cinv) {
    const int i = blockIdx.x * 256 + threadIdx.x;
    float m0 = pmax[i], m1 = pmax[(size_t)B_ * S_ + i];
    float m2 = pmax[(size_t)2 * B_ * S_ + i], m3 = pmax[(size_t)3 * B_ * S_ + i];
    float m = fmaxf(fmaxf(m0, m1), fmaxf(m2, m3));
    float s = psum[i] * expf(m0 - m)
            + psum[(size_t)B_ * S_ + i] * expf(m1 - m)
            + psum[(size_t)2 * B_ * S_ + i] * expf(m2 - m)
            + psum[(size_t)3 * B_ * S_ + i] * expf(m3 - m);
    cmax[i] = m;
    cinv[i] = 1.0f / s;
}

// ---------------------------------------------------------------------------
// K3: P_hat = exp(softmax(Wb,axis=T)) / 4, bf16.
__global__ __launch_bounds__(256) void k_pack(const u16* __restrict__ Wb,
                                              const float* __restrict__ cmax,
                                              const float* __restrict__ cinv,
                                              u16* __restrict__ P) {
    const size_t total8 = (size_t)B_ * T_ * S_ / 8;
    for (size_t i = (size_t)blockIdx.x * 256 + threadIdx.x; i < total8;
         i += (size_t)gridDim.x * 256) {
        size_t base = i * 8;
        int s = (int)(base & (S_ - 1));
        int b = (int)(base >> 19);
        uint4 xq = *(const uint4*)(Wb + base);
        UNPK(xq, x);
        float4 mA = *(const float4*)(cmax + (size_t)b * S_ + s);
        float4 mB = *(const float4*)(cmax + (size_t)b * S_ + s + 4);
        float4 iA = *(const float4*)(cinv + (size_t)b * S_ + s);
        float4 iB = *(const float4*)(cinv + (size_t)b * S_ + s + 4);
        float w0 = __builtin_amdgcn_exp2f(fmaf(x0, INV_LN2F, -mA.x * INV_LN2F)) * iA.x;
        float w1 = __builtin_amdgcn_exp2f(fmaf(x1, INV_LN2F, -mA.y * INV_LN2F)) * iA.y;
        float w2 = __builtin_amdgcn_exp2f(fmaf(x2, INV_LN2F, -mA.z * INV_LN2F)) * iA.z;
        float w3 = __builtin_amdgcn_exp2f(fmaf(x3, INV_LN2F, -mA.w * INV_LN2F)) * iA.w;
        float w4 = __builtin_amdgcn_exp2f(fmaf(x4, INV_LN2F, -mB.x * INV_LN2F)) * iB.x;
        float w5 = __builtin_amdgcn_exp2f(fmaf(x5, INV_LN2F, -mB.y * INV_LN2F)) * iB.y;
        float w6 = __builtin_amdgcn_exp2f(fmaf(x6, INV_LN2F, -mB.z * INV_LN2F)) * iB.z;
        float w7 = __builtin_amdgcn_exp2f(fmaf(x7, INV_LN2F, -mB.w * INV_LN2F)) * iB.w;
        float p0 = __builtin_amdgcn_exp2f(fmaf(w0, INV_LN2F, -2.0f));
        float p1 = __builtin_amdgcn_exp2f(fmaf(w1, INV_LN2F, -2.0f));
        float p2 = __builtin_amdgcn_exp2f(fmaf(w2, INV_LN2F, -2.0f));
        float p3 = __builtin_amdgcn_exp2f(fmaf(w3, INV_LN2F, -2.0f));
        float p4 = __builtin_amdgcn_exp2f(fmaf(w4, INV_LN2F, -2.0f));
        float p5 = __builtin_amdgcn_exp2f(fmaf(w5, INV_LN2F, -2.0f));
        float p6 = __builtin_amdgcn_exp2f(fmaf(w6, INV_LN2F, -2.0f));
        float p7 = __builtin_amdgcn_exp2f(fmaf(w7, INV_LN2F, -2.0f));
        *(uint4*)(P + base) = pack8f(p0, p1, p2, p3, p4, p5, p6, p7);
    }
}

// ---------------------------------------------------------------------------
// K4: backward DP, linear domain. 32 chunks of 32 + 32-step warm-up.
// 4-deep LDS ring (prefetch distance 3), vmcnt pipeline, DPP shift.
#define RENORM_B() do {                                                         \
    float mx_ = wave_fmax(fmaxf(fmaxf(fmaxf(m0,m1),fmaxf(m2,m3)),               \
                                fmaxf(fmaxf(m4,m5),fmaxf(m6,m7))));             \
    int eb_ = (__float_as_int(mx_) >> 23) & 255;                                \
    float sc_ = (eb_ > 0) ? __int_as_float((254 - eb_) << 23) : 1.0f;           \
    m0*=sc_; m1*=sc_; m2*=sc_; m3*=sc_; m4*=sc_; m5*=sc_; m6*=sc_; m7*=sc_;     \
} while (0)

#define BSTEPD(tt, jj) do {                                                     \
    uint4 q_ = *(const uint4*)&Pl[buf][jj][l8];                                 \
    UNPK(q_, eP);                                                               \
    float z0=m0*eP0, z1=m1*eP1, z2=m2*eP2, z3=m3*eP3;                           \
    float z4=m4*eP4, z5=m5*eP5, z6=m6*eP6, z7=m7*eP7;                           \
    float rt = fdpp0<0x130>(z0);  /* lane l <- l+1, lane63 -> 0 */              \
    m0=z0+z1; m1=z1+z2; m2=z2+z3; m3=z3+z4;                                     \
    m4=z4+z5; m5=z5+z6; m6=z6+z7; m7=z7+rt;                                     \
    if ((tt) < w0 + 32) {                                                       \
        uint4 st;                                                               \
        asm("v_cvt_pk_bf16_f32 %0, %1, %2" : "=v"(st.x) : "v"(m0), "v"(m1));    \
        asm("v_cvt_pk_bf16_f32 %0, %1, %2" : "=v"(st.y) : "v"(m2), "v"(m3));    \
        asm("v_cvt_pk_bf16_f32 %0, %1, %2" : "=v"(st.z) : "v"(m4), "v"(m5));    \
        asm("v_cvt_pk_bf16_f32 %0, %1, %2" : "=v"(st.w) : "v"(m6), "v"(m7));    \
        *(uint4*)(Bb + (size_t)(tt) * S_ + l8) = st;                            \
    }                                                                           \
} while (0)

#define BISSUE(g) do {                                                          \
    const int bs_ = te - 8 * (g);                                               \
    _Pragma("unroll")                                                           \
    for (int r = 0; r < 8; ++r)                                                 \
        gll16(Pb + (size_t)(bs_ - r) * S_ + l8, &Pl[(g) & 3][r][0]);            \
} while (0)

__global__ __launch_bounds__(64) void k_beta(const u16* __restrict__ P,
                                             u16* __restrict__ Bt) {
    __shared__ u16 Pl[4][8][S_];        // 32 KB
    const int l = threadIdx.x, l8 = l * 8;
    const int xcd = blockIdx.x & 7;
    const int idx = blockIdx.x >> 3;
    const int c = idx & 31;
    const int b = ((idx >> 5) << 3) + xcd;   // all chunks of b on one XCD
    const int w0 = c * 32;
    const u16* Pb = P  + (size_t)b * T_ * S_;
    u16*      Bb = Bt + (size_t)b * T_ * S_;
    float m0, m1, m2, m3, m4, m5, m6, m7;
    int te = w0 + 63;
    if (te > 1023) te = 1023;
    if (te == 1023) {    // exact init (c == 30, 31)
        m0 = m1 = m2 = m3 = m4 = m5 = m6 = 0.f;
        m7 = (l == 63) ? 1.f : 0.f;
        if (1023 < w0 + 32) {   // c == 31 stores init row
            uint4 st;
            asm("v_cvt_pk_bf16_f32 %0, %1, %2" : "=v"(st.x) : "v"(m0), "v"(m1));
            asm("v_cvt_pk_bf16_f32 %0, %1, %2" : "=v"(st.y) : "v"(m2), "v"(m3));
            asm("v_cvt_pk_bf16_f32 %0, %1, %2" : "=v"(st.z) : "v"(m4), "v"(m5));
            asm("v_cvt_pk_bf16_f32 %0, %1, %2" : "=v"(st.w) : "v"(m6), "v"(m7));
            *(uint4*)(Bb + (size_t)1023 * S_ + l8) = st;
        }
    } else {
        m0 = m1 = m2 = m3 = m4 = m5 = m6 = m7 = 1.f;
    }
    const int cnt = te - w0;            // 63/31, == 7 mod 8
    const int ng = (cnt + 1) >> 3;      // 8/4
    BISSUE(0);
    BISSUE(1);
    BISSUE(2);
    int tt = te - 1;
    int buf = 0;
    for (int g = 0; g < ng - 1; ++g) {
        WAITV(16);   // <=2 groups outstanding -> group g arrived
        BSTEPD(tt - 0, 0);  BSTEPD(tt - 1, 1);  BSTEPD(tt - 2, 2);  BSTEPD(tt - 3, 3);
        BSTEPD(tt - 4, 4);  BSTEPD(tt - 5, 5);  BSTEPD(tt - 6, 6);  BSTEPD(tt - 7, 7);
        RENORM_B();
        FENCE_LGKM();
        if (g + 3 < ng) BISSUE(g + 3);
        __builtin_amdgcn_sched_barrier(0);
        buf = (buf + 1) & 3;
        tt -= 8;
    }
    WAITV(0);
    BSTEPD(tt - 0, 0);  BSTEPD(tt - 1, 1);  BSTEPD(tt - 2, 2);  BSTEPD(tt - 3, 3);
    BSTEPD(tt - 4, 4);  BSTEPD(tt - 5, 5);  BSTEPD(tt - 6, 6);
}

// ---------------------------------------------------------------------------
// K5: fused mu-forward + Viterbi, linear domain, 32 chunks of 32, 32 warm-up,
// 4-deep LDS ring on both streams.
#define RENORM_MI() do {                                                        \
    float mx_ = wave_fmax(fmaxf(fmaxf(fmaxf(m0,m1),fmaxf(m2,m3)),               \
                                fmaxf(fmaxf(m4,m5),fmaxf(m6,m7))));             \
    int eb_ = (__float_as_int(mx_) >> 23) & 255;                                \
    float sc_ = (eb_ > 0) ? __int_as_float((254 - eb_) << 23) : 1.0f;           \
    if (eb_ > 0) ioffM += eb_ - 127;                                            \
    m0*=sc_; m1*=sc_; m2*=sc_; m3*=sc_; m4*=sc_; m5*=sc_; m6*=sc_; m7*=sc_;     \
} while (0)

#define RENORM_VR() do {                                                        \
    float mx_ = wave_fmax(fmaxf(fmaxf(fmaxf(v0,v1),fmaxf(v2,v3)),               \
                                fmaxf(fmaxf(v4,v5),fmaxf(v6,v7))));             \
    int eb_ = (__float_as_int(mx_) >> 23) & 255;                                \
    float sc_ = (eb_ > 0) ? __int_as_float((254 - eb_) << 23) : 0.0f;           \
    float ad_ = (eb_ > 0) ? 0.f : 1.f;                                          \
    v0=fmaf(v0,sc_,ad_); v1=fmaf(v1,sc_,ad_); v2=fmaf(v2,sc_,ad_);              \
    v3=fmaf(v3,sc_,ad_); v4=fmaf(v4,sc_,ad_); v5=fmaf(v5,sc_,ad_);              \
    v6=fmaf(v6,sc_,ad_); v7=fmaf(v7,sc_,ad_);                                   \
} while (0)

#define VSTEPD(TT, jj) do {                                                     \
    uint4 qp_ = *(const uint4*)&Pl[buf][jj][l8];                                 \
    uint4 qb_ = *(const uint4*)&Bl[buf][jj][l8];                                 \
    UNPK(qp_, eP); UNPK(qb_, eB);                                               \
    float lf = fdpp0<0x138>(m7);  /* lane l <- l-1, lane0 -> 0 */               \
    float n0 = eP0*(m0+lf), n1 = eP1*(m1+m0);                                   \
    float n2 = eP2*(m2+m1), n3 = eP3*(m3+m2);                                   \
    float n4 = eP4*(m4+m3), n5 = eP5*(m5+m4);                                   \
    float n6 = eP6*(m6+m5), n7 = eP7*(m7+m6);                                   \
    float vlf = fdpp0<0x138>(v7);                                               \
    if ((TT) >= w0) {                                                           \
        unsigned cc0=(vlf>v0)?1u:0u, cc1=(v0>v1)?2u:0u, cc2=(v1>v2)?4u:0u,      \
                 cc3=(v2>v3)?8u:0u,  cc4=(v3>v4)?16u:0u, cc5=(v4>v5)?32u:0u,    \
                 cc6=(v5>v6)?64u:0u, cc7=(v6>v7)?128u:0u;                       \
        acc |= ((u64)(cc0|cc1|cc2|cc3|cc4|cc5|cc6|cc7)) << (((TT)&7)*8);        \
        if (((TT)&7) == 7) { mrow[((TT)>>3)*64 + l] = acc; acc = 0ULL; }        \
    }                                                                           \
    float w0v=(n0*eB0)*fmaxf(v0,vlf), w1v=(n1*eB1)*fmaxf(v1,v0);                \
    float w2v=(n2*eB2)*fmaxf(v2,v1),  w3v=(n3*eB3)*fmaxf(v3,v2);                \
    float w4v=(n4*eB4)*fmaxf(v4,v3),  w5v=(n5*eB5)*fmaxf(v5,v4);                \
    float w6v=(n6*eB6)*fmaxf(v6,v5),  w7v=(n7*eB7)*fmaxf(v7,v6);                \
    m0=n0;m1=n1;m2=n2;m3=n3;m4=n4;m5=n5;m6=n6;m7=n7;                            \
    v0=w0v;v1=w1v;v2=w2v;v3=w3v;v4=w4v;v5=w5v;v6=w6v;v7=w7v;                    \
    if ((TT) == wexp) { wex = __shfl(m0, 2 * c); wio = ioffM; }                 \
} while (0)

#define VISSUE(g) do {                                                          \
    const int bs_ = t0 + 1 + 8 * (g);                                           \
    _Pragma("unroll")                                                           \
    for (int r = 0; r < 8; ++r) {                                               \
        gll16(Pb  + (size_t)(bs_ + r) * S_ + l8, &Pl[(g) & 3][r][0]);           \
        gll16(Btb + (size_t)(bs_ + r) * S_ + l8, &Bl[(g) & 3][r][0]);           \
    }                                                                           \
} while (0)

__global__ __launch_bounds__(64) void k_vit(const u16* __restrict__ P,
                                            const u16* __restrict__ Bt,
                                            u64* __restrict__ mbg,
                                            float* __restrict__ elog,
                                            float* __restrict__ wlg) {
    __shared__ u16 Pl[4][8][S_];        // 32 KB
    __shared__ u16 Bl[4][8][S_];        // 32 KB
    const int l = threadIdx.x, l8 = l * 8;
    const int xcd = blockIdx.x & 7;
    const int idx = blockIdx.x >> 3;
    const int c = idx & 31;
    const int b = ((idx >> 5) << 3) + xcd;
    const int w0 = c * 32, tend = w0 + 31;
    const int t0 = (w0 >= 32) ? (w0 - 32) : 0;
    const int wexp = w0 - 1;
    const u16* Pb  = P  + (size_t)b * T_ * S_;
    const u16* Btb = Bt + (size_t)b * T_ * S_;
    u64* mrow = mbg + (size_t)b * 8192;

    float m0,m1,m2,m3,m4,m5,m6,m7, v0,v1,v2,v3,v4,v5,v6,v7;
    int ioffM = 0;
    float wex = 1.f; int wio = 0;
    {
        uint4 qp = PROW(t0); UNPK(qp, eP);
        uint4 qb = BROW(t0); UNPK(qb, eB);
        if (t0 == 0) {   // exact init (c == 0, 1)
            m0 = (l == 0) ? eP0 : 0.f;
            m1 = 0.f; m2 = 0.f; m3 = 0.f; m4 = 0.f; m5 = 0.f; m6 = 0.f; m7 = 0.f;
        } else {
            m0 = eP0; m1 = eP1; m2 = eP2; m3 = eP3;
            m4 = eP4; m5 = eP5; m6 = eP6; m7 = eP7;
        }
        v0 = m0*eB0; v1 = m1*eB1; v2 = m2*eB2; v3 = m3*eB3;
        v4 = m4*eB4; v5 = m5*eB5; v6 = m6*eB6; v7 = m7*eB7;
    }
    u64 acc = 0ULL;
    const int cnt = tend - t0;          // 63/31
    const int ng = (cnt + 1) >> 3;      // 8/4
    VISSUE(0);
    VISSUE(1);
    VISSUE(2);
    int t = t0 + 1;
    int buf = 0;
    for (int g = 0; g < ng - 1; ++g) {
        WAITV(32);   // <=2 groups (16 loads each) outstanding -> group g arrived
        VSTEPD(t + 0, 0);  VSTEPD(t + 1, 1);  VSTEPD(t + 2, 2);  VSTEPD(t + 3, 3);
        VSTEPD(t + 4, 4);  VSTEPD(t + 5, 5);  VSTEPD(t + 6, 6);  VSTEPD(t + 7, 7);
        RENORM_MI();
        RENORM_VR();
        FENCE_LGKM();
        if (g + 3 < ng) VISSUE(g + 3);
        __builtin_amdgcn_sched_barrier(0);
        buf = (buf + 1) & 3;
        t += 8;
    }
    WAITV(0);
    VSTEPD(t + 0, 0);  VSTEPD(t + 1, 1);  VSTEPD(t + 2, 2);  VSTEPD(t + 3, 3);
    VSTEPD(t + 4, 4);  VSTEPD(t + 5, 5);  VSTEPD(t + 6, 6);

    float eex = (c == 31) ? __shfl(m7, 63) : __shfl(m0, 2 * (c + 1));
    if (l == 0) {
        elog[b * 32 + c] = __builtin_amdgcn_logf(fmaxf(eex, 1e-35f)) + (float)ioffM;
        if (c >= 1)
            wlg[b * 32 + c] = __builtin_amdgcn_logf(fmaxf(wex, 1e-35f)) + (float)wio;
    }
}

// ---------------------------------------------------------------------------
// K6a: per-(b,chunk) backtrace maps.
__global__ __launch_bounds__(512) void k_map(const u64* __restrict__ mbg,
                                             u16* __restrict__ map) {
    __shared__ u64 mb[4][64];   // 2 KB: taus 4c..4c+3
    const int b = blockIdx.x >> 5, c = blockIdx.x & 31;
    const int tid = threadIdx.x;
    const u64* src = mbg + (size_t)b * 8192 + (size_t)(4 * c) * 64;
    if (tid < 128) ((uint4*)&mb[0][0])[tid] = ((const uint4*)src)[tid];
    __syncthreads();
    int jj = tid;
    const int kmin = (c == 0) ? 1 : 0;
    for (int k = 31; k >= kmin; --k) {
        u64 word = mb[k >> 3][jj >> 3];
        jj -= (int)((word >> ((k & 7) * 8 + (jj & 7))) & 1ULL);
    }
    map[((size_t)b * 32 + c) * 512 + tid] = (u16)jj;
}

// K6b: compose maps then 32 lanes re-trace chunks in parallel.
__global__ __launch_bounds__(256) void k_btr2(const u64* __restrict__ mbg,
                                              const u16* __restrict__ map,
                                              int* __restrict__ js) {
    __shared__ u64 mb[128][64];   // 64 KB
    __shared__ u16 cent[32];
    const int b = blockIdx.x, tid = threadIdx.x;
    const uint4* src = (const uint4*)(mbg + (size_t)b * 8192);
    uint4* dst = (uint4*)&mb[0][0];
    for (int i = tid; i < 4096; i += 256) dst[i] = src[i];
    if (tid == 0) {
        int jj = 511;
        cent[31] = 511;
        for (int c = 31; c >= 1; --c) {
            jj = (int)map[((size_t)b * 32 + c) * 512 + jj];
            cent[c - 1] = (u16)jj;
        }
    }
    __syncthreads();
    if (tid < 32) {
        const int c = tid;
        int jj = (int)cent[c];
        js[b * T_ + 32 * c + 31] = jj;
        const int kmin = (c == 0) ? 1 : 0;
        for (int k = 31; k >= kmin; --k) {
            const int t = 32 * c + k;
            u64 word = mb[t >> 3][jj >> 3];
            jj -= (int)((word >> ((t & 7) * 8 + (jj & 7))) & 1ULL);
            js[b * T_ + t - 1] = jj;
        }
    }
}

// ---------------------------------------------------------------------------
// K7: fused one-hot path writer (blocks 0..4095) + logprobs (blocks 4096..4127).
__global__ __launch_bounds__(256) void k_out(const int* __restrict__ js,
                                             const u16* __restrict__ P,
                                             const float* __restrict__ lp_part,
                                             const int* __restrict__ tlen,
                                             const float* __restrict__ elog,
                                             const float* __restrict__ wlg,
                                             float* __restrict__ outp,
                                             float* __restrict__ out_lp) {
    if (blockIdx.x < 4096) {
        const size_t total4 = (size_t)B_ * T_ * S_ / 4;
        float4* O = (float4*)outp;
        for (size_t i = (size_t)blockIdx.x * 256 + threadIdx.x; i < total4;
             i += (size_t)4096 * 256) {
            size_t base = i * 4;
            int s = (int)(base & (S_ - 1));
            int row = (int)(base >> 9);
            int jt = js[row];
            float4 o;
            o.x = (s == jt) ? 1.f : 0.f;
            o.y = (s + 1 == jt) ? 1.f : 0.f;
            o.z = (s + 2 == jt) ? 1.f : 0.f;
            o.w = (s + 3 == jt) ? 1.f : 0.f;
            O[i] = o;
        }
    } else {
        const int b = blockIdx.x - 4096;
        float acc = 0.f;
        for (int t = threadIdx.x; t < T_; t += 256) {
            int jt = js[b * T_ + t];
            unsigned u = P[((size_t)b * T_ + t) * S_ + jt];
            acc += __builtin_amdgcn_logf(__uint_as_float(u << 16));
        }
        __shared__ float red[256];
        red[threadIdx.x] = acc;
        __syncthreads();
        for (int o = 128; o > 0; o >>= 1) {
            if (threadIdx.x < o) red[threadIdx.x] += red[threadIdx.x + o];
            __syncthreads();
        }
        if (threadIdx.x == 0) {
            float basep = 0.f;
            for (int i = 0; i < 48; ++i) basep += lp_part[b * 48 + i];
            float mu2n = elog[b * 32 + 31];
            for (int cc = 1; cc < 32; ++cc)
                mu2n += elog[b * 32 + cc - 1] - wlg[b * 32 + cc];
            out_lp[b] = basep - HALF_LOG_2PI * ((float)tlen[b] * C_)
                        + LN2F * (red[0] - mu2n);
        }
    }
}

// ---------------------------------------------------------------------------
extern "C" void kernel_launch(void* const* d_in, const int* in_sizes, int n_in,
                              void* d_out, int out_size, void* d_ws, size_t ws_size,
                              hipStream_t stream) {
    const float* eps  = (const float*)d_in[0];
    const float* cond = (const float*)d_in[1];
    const int* tlen   = (const int*)d_in[2];

    float* out_path = (float*)d_out;
    float* out_lp   = out_path + (size_t)B_ * T_ * S_;

    const size_t NBTS = (size_t)B_ * T_ * S_;
    char* w = (char*)d_ws;
    u16*   Wb   = (u16*)w;                            // 34 MB bf16 logits
    u16*   P    = Wb + NBTS;                          // 34 MB bf16 exp(W)/4
    u16*   Bt   = P + NBTS;                           // 34 MB bf16 linear beta
    u64*   mbg  = (u64*)(Bt + NBTS);                  // 2 MB move bits
    float* pmax = (float*)(mbg + (size_t)B_ * 8192);
    float* psum = pmax + (size_t)4 * B_ * S_;
    float* cmax = psum + (size_t)4 * B_ * S_;
    float* cinv = cmax + (size_t)B_ * S_;
    float* lp_part = cinv + (size_t)B_ * S_;
    float* elog = lp_part + B_ * 48;                  // B*32
    float* wlg  = elog + B_ * 32;                     // B*32
    int*   js   = (int*)(wlg + B_ * 32);              // B*T
    u16*   map  = (u16*)(js + B_ * T_);               // 1 MB backtrace maps

    k_eps<<<B_ * 48, 256, 0, stream>>>(eps, tlen, lp_part);
    k_gemm<<<dim3(S_ / 128, T_ / 128, B_), 256, 0, stream>>>(eps, cond, Wb);
    k_stats1<<<B_ * 4, 256, 0, stream>>>(Wb, pmax, psum);
    k_stats2<<<B_ * S_ / 256, 256, 0, stream>>>(pmax, psum, cmax, cinv);
    k_pack<<<2048, 256, 0, stream>>>(Wb, cmax, cinv, P);
    k_beta<<<B_ * 32, 64, 0, stream>>>(P, Bt);
    k_vit<<<B_ * 32, 64, 0, stream>>>(P, Bt, mbg, elog, wlg);
    k_map<<<B_ * 32, 512, 0, stream>>>(mbg, map);
    k_btr2<<<B_, 256, 0, stream>>>(mbg, map, js);
    k_out<<<4096 + B_, 256, 0, stream>>>(js, P, lp_part, tlen, elog, wlg,
                                         out_path, out_lp);
}

// Round 13
// 169.089 us; speedup vs baseline: 1.0649x; 1.0649x over previous
//
#include <hip/hip_runtime.h>
#include <cstdint>
#include <cstddef>

#define B_ 32
#define T_ 1024
#define S_ 512
#define C_ 384
#define HALF_LOG_2PI 0.91893853320467274178f
#define LN2F 0.69314718055994530942f
#define INV_LN2F 1.44269504088896340736f

typedef unsigned short u16;
typedef unsigned long long u64;
typedef __attribute__((ext_vector_type(8))) short bf16x8;
typedef __attribute__((ext_vector_type(4))) float f32x4;

__device__ __forceinline__ unsigned rne16(float f) {   // f32 -> bf16 bits (RNE)
    unsigned b = __float_as_uint(f);
    return (b + 0x7FFFu + ((b >> 16) & 1u)) >> 16;
}
__device__ __forceinline__ uint4 pack8f(float a0, float a1, float a2, float a3,
                                        float a4, float a5, float a6, float a7) {
    uint4 q;
    q.x = rne16(a0) | (rne16(a1) << 16);
    q.y = rne16(a2) | (rne16(a3) << 16);
    q.z = rne16(a4) | (rne16(a5) << 16);
    q.w = rne16(a6) | (rne16(a7) << 16);
    return q;
}
#define UNPK(q, p)                                                              \
    float p##0 = __uint_as_float((q).x << 16),                                  \
          p##1 = __uint_as_float((q).x & 0xFFFF0000u),                          \
          p##2 = __uint_as_float((q).y << 16),                                  \
          p##3 = __uint_as_float((q).y & 0xFFFF0000u),                          \
          p##4 = __uint_as_float((q).z << 16),                                  \
          p##5 = __uint_as_float((q).z & 0xFFFF0000u),                          \
          p##6 = __uint_as_float((q).w << 16),                                  \
          p##7 = __uint_as_float((q).w & 0xFFFF0000u)

#define PROW(t) (*(const uint4*)(Pb  + (size_t)(t) * S_ + l8))
#define BROW(t) (*(const uint4*)(Btb + (size_t)(t) * S_ + l8))

// ---------------------------------------------------------------------------
// DPP helpers: VALU-only cross-lane.
template <int CTRL>
__device__ __forceinline__ float fdpp0(float x) {     // invalid src lanes -> 0
    return __uint_as_float((unsigned)__builtin_amdgcn_update_dpp(
        0, (int)__float_as_uint(x), CTRL, 0xF, 0xF, true));
}
__device__ __forceinline__ float wave_fmax(float x) { // uniform full-wave max
    x = fmaxf(x, fdpp0<0x121>(x));   // row_ror:1
    x = fmaxf(x, fdpp0<0x122>(x));   // row_ror:2
    x = fmaxf(x, fdpp0<0x124>(x));   // row_ror:4
    x = fmaxf(x, fdpp0<0x128>(x));   // row_ror:8
    float a = __uint_as_float((unsigned)__builtin_amdgcn_readlane((int)__float_as_uint(x), 0));
    float b = __uint_as_float((unsigned)__builtin_amdgcn_readlane((int)__float_as_uint(x), 16));
    float c = __uint_as_float((unsigned)__builtin_amdgcn_readlane((int)__float_as_uint(x), 32));
    float d = __uint_as_float((unsigned)__builtin_amdgcn_readlane((int)__float_as_uint(x), 48));
    return fmaxf(fmaxf(a, b), fmaxf(c, d));
}

__device__ __forceinline__ void gll16(const u16* g, u16* l) {
    __builtin_amdgcn_global_load_lds(
        (const __attribute__((address_space(1))) void*)g,
        (__attribute__((address_space(3))) void*)l, 16, 0, 0);
}
#define WAITV(N) do { asm volatile("s_waitcnt vmcnt(" #N ")" ::: "memory");     \
                      __builtin_amdgcn_sched_barrier(0); } while (0)
#define FENCE_LGKM() do { asm volatile("s_waitcnt lgkmcnt(0)" ::: "memory");    \
                          __builtin_amdgcn_sched_barrier(0); } while (0)

// ---------------------------------------------------------------------------
// K0: fused eps->bf16 + eps^2 partials (blocks 0..1535) and cond->bf16 (rest).
__global__ __launch_bounds__(256) void k_pre(const float* __restrict__ eps,
                                             const float* __restrict__ cond,
                                             const int* __restrict__ tlen,
                                             float* __restrict__ lp_part,
                                             u16* __restrict__ Abf,
                                             u16* __restrict__ Bbf) {
    if (blockIdx.x < 1536) {
        const int b = blockIdx.x / 48, chunk = blockIdx.x % 48;
        const int len = tlen[b];
        const float* base = eps + (size_t)b * T_ * C_ + (size_t)chunk * 8192;
        u16* obase = Abf + (size_t)b * T_ * C_ + (size_t)chunk * 8192;
        float acc = 0.f;
        for (int g = threadIdx.x; g < 1024; g += 256) {
            float4 v0 = *(const float4*)(base + g * 8);
            float4 v1 = *(const float4*)(base + g * 8 + 4);
            int t = (chunk * 8192 + g * 8) / C_;
            if (t < len)
                acc += v0.x*v0.x + v0.y*v0.y + v0.z*v0.z + v0.w*v0.w
                     + v1.x*v1.x + v1.y*v1.y + v1.z*v1.z + v1.w*v1.w;
            *(uint4*)(obase + g * 8) = pack8f(v0.x, v0.y, v0.z, v0.w,
                                              v1.x, v1.y, v1.z, v1.w);
        }
        __shared__ float red[256];
        red[threadIdx.x] = acc;
        __syncthreads();
        for (int o = 128; o > 0; o >>= 1) {
            if (threadIdx.x < o) red[threadIdx.x] += red[threadIdx.x + o];
            __syncthreads();
        }
        if (threadIdx.x == 0) lp_part[blockIdx.x] = -0.5f * red[0];
    } else {
        const size_t n8 = (size_t)B_ * S_ * C_ / 8;
        for (size_t i = (size_t)(blockIdx.x - 1536) * 256 + threadIdx.x; i < n8;
             i += (size_t)512 * 256) {
            float4 v0 = *(const float4*)(cond + i * 8);
            float4 v1 = *(const float4*)(cond + i * 8 + 4);
            *(uint4*)(Bbf + i * 8) = pack8f(v0.x, v0.y, v0.z, v0.w,
                                            v1.x, v1.y, v1.z, v1.w);
        }
    }
}

// ---------------------------------------------------------------------------
// K1: bf16 MFMA GEMM -> bf16 logits Wb. 128x128 tile, 4 waves, BK=32.
// 1-D grid, XCD-swizzled: all 32 tiles of a batch land on one XCD so the
// 1.2 MB bf16 A+B panels stay L2-resident (fetched ~once per batch).
__global__ __launch_bounds__(256) void k_gemm(const u16* __restrict__ A,
                                              const u16* __restrict__ Bc,
                                              u16* __restrict__ Wb) {
    __shared__ u16 Al[4096];
    __shared__ u16 Bl[4096];
    const int wgid = blockIdx.x;
    const int xcd  = wgid & 7;
    const int rest = wgid >> 3;            // 0..127
    const int b    = (rest >> 5) * 8 + xcd;
    const int tile = rest & 31;            // 0..31 = (m,n) tile
    const int m0 = (tile >> 2) * 128;
    const int n0 = (tile & 3) * 128;
    const int tid = threadIdx.x;
    const int lane = tid & 63, wid = tid >> 6;
    const int wy = wid >> 1, wx = wid & 1;
    const int r15 = lane & 15, kg = lane >> 4;
    const u16* Ab = A  + (size_t)b * T_ * C_;
    const u16* Bb = Bc + (size_t)b * S_ * C_;

    f32x4 acc[4][4];
#pragma unroll
    for (int i = 0; i < 4; ++i)
#pragma unroll
        for (int j = 0; j < 4; ++j) acc[i][j] = (f32x4){0.f, 0.f, 0.f, 0.f};

    const int row0 = tid >> 2, o0 = tid & 3;
    const int row1 = row0 + 64;
    const int wb0 = (row0 * 64 + o0 * 16) ^ (((row0 >> 1) & 7) << 4);
    const int wb1 = (row1 * 64 + o0 * 16) ^ (((row1 >> 1) & 7) << 4);
    const int rswz = ((r15 >> 1) & 7) << 4;

    for (int k0 = 0; k0 < C_; k0 += 32) {
        uint4 a0 = *(const uint4*)(Ab + (size_t)(m0 + row0) * C_ + k0 + o0 * 8);
        uint4 a1 = *(const uint4*)(Ab + (size_t)(m0 + row1) * C_ + k0 + o0 * 8);
        uint4 c0 = *(const uint4*)(Bb + (size_t)(n0 + row0) * C_ + k0 + o0 * 8);
        uint4 c1 = *(const uint4*)(Bb + (size_t)(n0 + row1) * C_ + k0 + o0 * 8);
        __syncthreads();
        *(uint4*)((char*)Al + wb0) = a0;
        *(uint4*)((char*)Al + wb1) = a1;
        *(uint4*)((char*)Bl + wb0) = c0;
        *(uint4*)((char*)Bl + wb1) = c1;
        __syncthreads();
        bf16x8 af[4], bfb[4];
#pragma unroll
        for (int ar = 0; ar < 4; ++ar) {
            int row = wy * 64 + ar * 16 + r15;
            af[ar] = *(const bf16x8*)((const char*)Al + ((row * 64 + kg * 16) ^ rswz));
        }
#pragma unroll
        for (int bc = 0; bc < 4; ++bc) {
            int row = wx * 64 + bc * 16 + r15;
            bfb[bc] = *(const bf16x8*)((const char*)Bl + ((row * 64 + kg * 16) ^ rswz));
        }
#pragma unroll
        for (int ar = 0; ar < 4; ++ar)
#pragma unroll
            for (int bc = 0; bc < 4; ++bc)
                acc[ar][bc] = __builtin_amdgcn_mfma_f32_16x16x32_bf16(
                    af[ar], bfb[bc], acc[ar][bc], 0, 0, 0);
    }
#pragma unroll
    for (int ar = 0; ar < 4; ++ar) {
        int t = m0 + wy * 64 + ar * 16 + kg * 4;
#pragma unroll
        for (int bc = 0; bc < 4; ++bc) {
            int s = n0 + wx * 64 + bc * 16 + r15;
            u16* dst = Wb + ((size_t)b * T_ + t) * S_ + s;
#pragma unroll
            for (int r = 0; r < 4; ++r) dst[(size_t)r * S_] = (u16)rne16(acc[ar][bc][r]);
        }
    }
}

// ---------------------------------------------------------------------------
// K2a: column stats over 256-row chunk. 4 waves, 8 cols/lane, uint4 row loads.
#define COLU(i, xa, xb, xc, xd) do {                                            \
    float nm = fmaxf(fmaxf(fmaxf(m[i], xa), xb), fmaxf(xc, xd));                \
    s[i] = s[i] * __builtin_amdgcn_exp2f((m[i] - nm) * INV_LN2F)                \
         + __builtin_amdgcn_exp2f((xa - nm) * INV_LN2F)                         \
         + __builtin_amdgcn_exp2f((xb - nm) * INV_LN2F)                         \
         + __builtin_amdgcn_exp2f((xc - nm) * INV_LN2F)                         \
         + __builtin_amdgcn_exp2f((xd - nm) * INV_LN2F);                        \
    m[i] = nm;                                                                  \
} while (0)

__global__ __launch_bounds__(256) void k_stats1(const u16* __restrict__ Wb,
                                                float* __restrict__ pmax,
                                                float* __restrict__ psum) {
    __shared__ float smax[4][S_];
    __shared__ float ssum[4][S_];
    const int c = blockIdx.x & 3;
    const int b = blockIdx.x >> 2;
    const int w = threadIdx.x >> 6, l = threadIdx.x & 63;
    const u16* base = Wb + (size_t)b * T_ * S_ + (size_t)(c * 256 + w * 64) * S_ + l * 8;
    float m[8], s[8];
#pragma unroll
    for (int i = 0; i < 8; ++i) { m[i] = -3.0e38f; s[i] = 0.f; }
    for (int t = 0; t < 64; t += 4) {
        uint4 q0 = *(const uint4*)(base + (size_t)(t + 0) * S_);
        uint4 q1 = *(const uint4*)(base + (size_t)(t + 1) * S_);
        uint4 q2 = *(const uint4*)(base + (size_t)(t + 2) * S_);
        uint4 q3 = *(const uint4*)(base + (size_t)(t + 3) * S_);
        UNPK(q0, xa); UNPK(q1, xb); UNPK(q2, xc); UNPK(q3, xd);
        COLU(0, xa0, xb0, xc0, xd0);
        COLU(1, xa1, xb1, xc1, xd1);
        COLU(2, xa2, xb2, xc2, xd2);
        COLU(3, xa3, xb3, xc3, xd3);
        COLU(4, xa4, xb4, xc4, xd4);
        COLU(5, xa5, xb5, xc5, xd5);
        COLU(6, xa6, xb6, xc6, xd6);
        COLU(7, xa7, xb7, xc7, xd7);
    }
#pragma unroll
    for (int i = 0; i < 8; ++i) {
        smax[w][l * 8 + i] = m[i];
        ssum[w][l * 8 + i] = s[i];
    }
    __syncthreads();
    for (int col = threadIdx.x; col < S_; col += 256) {
        float m0 = smax[0][col], m1 = smax[1][col];
        float m2 = smax[2][col], m3 = smax[3][col];
        float nm = fmaxf(fmaxf(m0, m1), fmaxf(m2, m3));
        float ss = ssum[0][col] * __builtin_amdgcn_exp2f((m0 - nm) * INV_LN2F)
                 + ssum[1][col] * __builtin_amdgcn_exp2f((m1 - nm) * INV_LN2F)
                 + ssum[2][col] * __builtin_amdgcn_exp2f((m2 - nm) * INV_LN2F)
                 + ssum[3][col] * __builtin_amdgcn_exp2f((m3 - nm) * INV_LN2F);
        pmax[(size_t)c * B_ * S_ + b * S_ + col] = nm;
        psum[(size_t)c * B_ * S_ + b * S_ + col] = ss;
    }
}

__global__ __launch_bounds__(256) void k_stats2(const float* __restrict__ pmax,
                                                const float* __restrict__ psum,
                                                float* __restrict__ cmax,
                                                float* __restrict__ cinv) {
    const int i = blockIdx.x * 256 + threadIdx.x;
    float m0 = pmax[i], m1 = pmax[(size_t)B_ * S_ + i];
    float m2 = pmax[(size_t)2 * B_ * S_ + i], m3 = pmax[(size_t)3 * B_ * S_ + i];
    float m = fmaxf(fmaxf(m0, m1), fmaxf(m2, m3));
    float s = psum[i] * expf(m0 - m)
            + psum[(size_t)B_ * S_ + i] * expf(m1 - m)
            + psum[(size_t)2 * B_ * S_ + i] * expf(m2 - m)
            + psum[(size_t)3 * B_ * S_ + i] * expf(m3 - m);
    cmax[i] = m;
    cinv[i] = 1.0f / s;
}

// ---------------------------------------------------------------------------
// K3: P_hat = exp(softmax(Wb,axis=T)) / 4, bf16.
__global__ __launch_bounds__(256) void k_pack(const u16* __restrict__ Wb,
                                              const float* __restrict__ cmax,
                                              const float* __restrict__ cinv,
                                              u16* __restrict__ P) {
    const size_t total8 = (size_t)B_ * T_ * S_ / 8;
    for (size_t i = (size_t)blockIdx.x * 256 + threadIdx.x; i < total8;
         i += (size_t)gridDim.x * 256) {
        size_t base = i * 8;
        int s = (int)(base & (S_ - 1));
        int b = (int)(base >> 19);
        uint4 xq = *(const uint4*)(Wb + base);
        UNPK(xq, x);
        float4 mA = *(const float4*)(cmax + (size_t)b * S_ + s);
        float4 mB = *(const float4*)(cmax + (size_t)b * S_ + s + 4);
        float4 iA = *(const float4*)(cinv + (size_t)b * S_ + s);
        float4 iB = *(const float4*)(cinv + (size_t)b * S_ + s + 4);
        float w0 = __builtin_amdgcn_exp2f(fmaf(x0, INV_LN2F, -mA.x * INV_LN2F)) * iA.x;
        float w1 = __builtin_amdgcn_exp2f(fmaf(x1, INV_LN2F, -mA.y * INV_LN2F)) * iA.y;
        float w2 = __builtin_amdgcn_exp2f(fmaf(x2, INV_LN2F, -mA.z * INV_LN2F)) * iA.z;
        float w3 = __builtin_amdgcn_exp2f(fmaf(x3, INV_LN2F, -mA.w * INV_LN2F)) * iA.w;
        float w4 = __builtin_amdgcn_exp2f(fmaf(x4, INV_LN2F, -mB.x * INV_LN2F)) * iB.x;
        float w5 = __builtin_amdgcn_exp2f(fmaf(x5, INV_LN2F, -mB.y * INV_LN2F)) * iB.y;
        float w6 = __builtin_amdgcn_exp2f(fmaf(x6, INV_LN2F, -mB.z * INV_LN2F)) * iB.z;
        float w7 = __builtin_amdgcn_exp2f(fmaf(x7, INV_LN2F, -mB.w * INV_LN2F)) * iB.w;
        float p0 = __builtin_amdgcn_exp2f(fmaf(w0, INV_LN2F, -2.0f));
        float p1 = __builtin_amdgcn_exp2f(fmaf(w1, INV_LN2F, -2.0f));
        float p2 = __builtin_amdgcn_exp2f(fmaf(w2, INV_LN2F, -2.0f));
        float p3 = __builtin_amdgcn_exp2f(fmaf(w3, INV_LN2F, -2.0f));
        float p4 = __builtin_amdgcn_exp2f(fmaf(w4, INV_LN2F, -2.0f));
        float p5 = __builtin_amdgcn_exp2f(fmaf(w5, INV_LN2F, -2.0f));
        float p6 = __builtin_amdgcn_exp2f(fmaf(w6, INV_LN2F, -2.0f));
        float p7 = __builtin_amdgcn_exp2f(fmaf(w7, INV_LN2F, -2.0f));
        *(uint4*)(P + base) = pack8f(p0, p1, p2, p3, p4, p5, p6, p7);
    }
}

// ---------------------------------------------------------------------------
// K4: backward DP, linear domain. 32 chunks of 32 + 32-step warm-up.
// 4-deep LDS ring (prefetch distance 3), vmcnt pipeline, DPP shift.
#define RENORM_B() do {                                                         \
    float mx_ = wave_fmax(fmaxf(fmaxf(fmaxf(m0,m1),fmaxf(m2,m3)),               \
                                fmaxf(fmaxf(m4,m5),fmaxf(m6,m7))));             \
    int eb_ = (__float_as_int(mx_) >> 23) & 255;                                \
    float sc_ = (eb_ > 0) ? __int_as_float((254 - eb_) << 23) : 1.0f;           \
    m0*=sc_; m1*=sc_; m2*=sc_; m3*=sc_; m4*=sc_; m5*=sc_; m6*=sc_; m7*=sc_;     \
} while (0)

#define BSTEPD(tt, jj) do {                                                     \
    uint4 q_ = *(const uint4*)&Pl[buf][jj][l8];                                 \
    UNPK(q_, eP);                                                               \
    float z0=m0*eP0, z1=m1*eP1, z2=m2*eP2, z3=m3*eP3;                           \
    float z4=m4*eP4, z5=m5*eP5, z6=m6*eP6, z7=m7*eP7;                           \
    float rt = fdpp0<0x130>(z0);  /* lane l <- l+1, lane63 -> 0 */              \
    m0=z0+z1; m1=z1+z2; m2=z2+z3; m3=z3+z4;                                     \
    m4=z4+z5; m5=z5+z6; m6=z6+z7; m7=z7+rt;                                     \
    if ((tt) < w0 + 32) {                                                       \
        uint4 st;                                                               \
        asm("v_cvt_pk_bf16_f32 %0, %1, %2" : "=v"(st.x) : "v"(m0), "v"(m1));    \
        asm("v_cvt_pk_bf16_f32 %0, %1, %2" : "=v"(st.y) : "v"(m2), "v"(m3));    \
        asm("v_cvt_pk_bf16_f32 %0, %1, %2" : "=v"(st.z) : "v"(m4), "v"(m5));    \
        asm("v_cvt_pk_bf16_f32 %0, %1, %2" : "=v"(st.w) : "v"(m6), "v"(m7));    \
        *(uint4*)(Bb + (size_t)(tt) * S_ + l8) = st;                            \
    }                                                                           \
} while (0)

#define BISSUE(g) do {                                                          \
    const int bs_ = te - 8 * (g);                                               \
    _Pragma("unroll")                                                           \
    for (int r = 0; r < 8; ++r)                                                 \
        gll16(Pb + (size_t)(bs_ - r) * S_ + l8, &Pl[(g) & 3][r][0]);            \
} while (0)

__global__ __launch_bounds__(64) void k_beta(const u16* __restrict__ P,
                                             u16* __restrict__ Bt) {
    __shared__ u16 Pl[4][8][S_];        // 32 KB
    const int l = threadIdx.x, l8 = l * 8;
    const int xcd = blockIdx.x & 7;
    const int idx = blockIdx.x >> 3;
    const int c = idx & 31;
    const int b = ((idx >> 5) << 3) + xcd;   // all chunks of b on one XCD
    const int w0 = c * 32;
    const u16* Pb = P  + (size_t)b * T_ * S_;
    u16*      Bb = Bt + (size_t)b * T_ * S_;
    float m0, m1, m2, m3, m4, m5, m6, m7;
    int te = w0 + 63;
    if (te > 1023) te = 1023;
    if (te == 1023) {    // exact init (c == 30, 31)
        m0 = m1 = m2 = m3 = m4 = m5 = m6 = 0.f;
        m7 = (l == 63) ? 1.f : 0.f;
        if (1023 < w0 + 32) {   // c == 31 stores init row
            uint4 st;
            asm("v_cvt_pk_bf16_f32 %0, %1, %2" : "=v"(st.x) : "v"(m0), "v"(m1));
            asm("v_cvt_pk_bf16_f32 %0, %1, %2" : "=v"(st.y) : "v"(m2), "v"(m3));
            asm("v_cvt_pk_bf16_f32 %0, %1, %2" : "=v"(st.z) : "v"(m4), "v"(m5));
            asm("v_cvt_pk_bf16_f32 %0, %1, %2" : "=v"(st.w) : "v"(m6), "v"(m7));
            *(uint4*)(Bb + (size_t)1023 * S_ + l8) = st;
        }
    } else {
        m0 = m1 = m2 = m3 = m4 = m5 = m6 = m7 = 1.f;
    }
    const int cnt = te - w0;            // 63/31, == 7 mod 8
    const int ng = (cnt + 1) >> 3;      // 8/4
    BISSUE(0);
    BISSUE(1);
    BISSUE(2);
    int tt = te - 1;
    int buf = 0;
    for (int g = 0; g < ng - 1; ++g) {
        WAITV(16);   // <=2 groups outstanding -> group g arrived
        BSTEPD(tt - 0, 0);  BSTEPD(tt - 1, 1);  BSTEPD(tt - 2, 2);  BSTEPD(tt - 3, 3);
        BSTEPD(tt - 4, 4);  BSTEPD(tt - 5, 5);  BSTEPD(tt - 6, 6);  BSTEPD(tt - 7, 7);
        RENORM_B();
        FENCE_LGKM();
        if (g + 3 < ng) BISSUE(g + 3);
        __builtin_amdgcn_sched_barrier(0);
        buf = (buf + 1) & 3;
        tt -= 8;
    }
    WAITV(0);
    BSTEPD(tt - 0, 0);  BSTEPD(tt - 1, 1);  BSTEPD(tt - 2, 2);  BSTEPD(tt - 3, 3);
    BSTEPD(tt - 4, 4);  BSTEPD(tt - 5, 5);  BSTEPD(tt - 6, 6);
}

// ---------------------------------------------------------------------------
// K5: fused mu-forward + Viterbi, linear domain, 32 chunks of 32, 32 warm-up,
// 4-deep LDS ring on both streams.
#define RENORM_MI() do {                                                        \
    float mx_ = wave_fmax(fmaxf(fmaxf(fmaxf(m0,m1),fmaxf(m2,m3)),               \
                                fmaxf(fmaxf(m4,m5),fmaxf(m6,m7))));             \
    int eb_ = (__float_as_int(mx_) >> 23) & 255;                                \
    float sc_ = (eb_ > 0) ? __int_as_float((254 - eb_) << 23) : 1.0f;           \
    if (eb_ > 0) ioffM += eb_ - 127;                                            \
    m0*=sc_; m1*=sc_; m2*=sc_; m3*=sc_; m4*=sc_; m5*=sc_; m6*=sc_; m7*=sc_;     \
} while (0)

#define RENORM_VR() do {                                                        \
    float mx_ = wave_fmax(fmaxf(fmaxf(fmaxf(v0,v1),fmaxf(v2,v3)),               \
                                fmaxf(fmaxf(v4,v5),fmaxf(v6,v7))));             \
    int eb_ = (__float_as_int(mx_) >> 23) & 255;                                \
    float sc_ = (eb_ > 0) ? __int_as_float((254 - eb_) << 23) : 0.0f;           \
    float ad_ = (eb_ > 0) ? 0.f : 1.f;                                          \
    v0=fmaf(v0,sc_,ad_); v1=fmaf(v1,sc_,ad_); v2=fmaf(v2,sc_,ad_);              \
    v3=fmaf(v3,sc_,ad_); v4=fmaf(v4,sc_,ad_); v5=fmaf(v5,sc_,ad_);              \
    v6=fmaf(v6,sc_,ad_); v7=fmaf(v7,sc_,ad_);                                   \
} while (0)

#define VSTEPD(TT, jj) do {                                                     \
    uint4 qp_ = *(const uint4*)&Pl[buf][jj][l8];                                 \
    uint4 qb_ = *(const uint4*)&Bl[buf][jj][l8];                                 \
    UNPK(qp_, eP); UNPK(qb_, eB);                                               \
    float lf = fdpp0<0x138>(m7);  /* lane l <- l-1, lane0 -> 0 */               \
    float n0 = eP0*(m0+lf), n1 = eP1*(m1+m0);                                   \
    float n2 = eP2*(m2+m1), n3 = eP3*(m3+m2);                                   \
    float n4 = eP4*(m4+m3), n5 = eP5*(m5+m4);                                   \
    float n6 = eP6*(m6+m5), n7 = eP7*(m7+m6);                                   \
    float vlf = fdpp0<0x138>(v7);                                               \
    if ((TT) >= w0) {                                                           \
        unsigned cc0=(vlf>v0)?1u:0u, cc1=(v0>v1)?2u:0u, cc2=(v1>v2)?4u:0u,      \
                 cc3=(v2>v3)?8u:0u,  cc4=(v3>v4)?16u:0u, cc5=(v4>v5)?32u:0u,    \
                 cc6=(v5>v6)?64u:0u, cc7=(v6>v7)?128u:0u;                       \
        acc |= ((u64)(cc0|cc1|cc2|cc3|cc4|cc5|cc6|cc7)) << (((TT)&7)*8);        \
        if (((TT)&7) == 7) { mrow[((TT)>>3)*64 + l] = acc; acc = 0ULL; }        \
    }                                                                           \
    float w0v=(n0*eB0)*fmaxf(v0,vlf), w1v=(n1*eB1)*fmaxf(v1,v0);                \
    float w2v=(n2*eB2)*fmaxf(v2,v1),  w3v=(n3*eB3)*fmaxf(v3,v2);                \
    float w4v=(n4*eB4)*fmaxf(v4,v3),  w5v=(n5*eB5)*fmaxf(v5,v4);                \
    float w6v=(n6*eB6)*fmaxf(v6,v5),  w7v=(n7*eB7)*fmaxf(v7,v6);                \
    m0=n0;m1=n1;m2=n2;m3=n3;m4=n4;m5=n5;m6=n6;m7=n7;                            \
    v0=w0v;v1=w1v;v2=w2v;v3=w3v;v4=w4v;v5=w5v;v6=w6v;v7=w7v;                    \
    if ((TT) == wexp) { wex = __shfl(m0, 2 * c); wio = ioffM; }                 \
} while (0)

#define VISSUE(g) do {                                                          \
    const int bs_ = t0 + 1 + 8 * (g);                                           \
    _Pragma("unroll")                                                           \
    for (int r = 0; r < 8; ++r) {                                               \
        gll16(Pb  + (size_t)(bs_ + r) * S_ + l8, &Pl[(g) & 3][r][0]);           \
        gll16(Btb + (size_t)(bs_ + r) * S_ + l8, &Bl[(g) & 3][r][0]);           \
    }                                                                           \
} while (0)

__global__ __launch_bounds__(64) void k_vit(const u16* __restrict__ P,
                                            const u16* __restrict__ Bt,
                                            u64* __restrict__ mbg,
                                            float* __restrict__ elog,
                                            float* __restrict__ wlg) {
    __shared__ u16 Pl[4][8][S_];        // 32 KB
    __shared__ u16 Bl[4][8][S_];        // 32 KB
    const int l = threadIdx.x, l8 = l * 8;
    const int xcd = blockIdx.x & 7;
    const int idx = blockIdx.x >> 3;
    const int c = idx & 31;
    const int b = ((idx >> 5) << 3) + xcd;
    const int w0 = c * 32, tend = w0 + 31;
    const int t0 = (w0 >= 32) ? (w0 - 32) : 0;
    const int wexp = w0 - 1;
    const u16* Pb  = P  + (size_t)b * T_ * S_;
    const u16* Btb = Bt + (size_t)b * T_ * S_;
    u64* mrow = mbg + (size_t)b * 8192;

    float m0,m1,m2,m3,m4,m5,m6,m7, v0,v1,v2,v3,v4,v5,v6,v7;
    int ioffM = 0;
    float wex = 1.f; int wio = 0;
    {
        uint4 qp = PROW(t0); UNPK(qp, eP);
        uint4 qb = BROW(t0); UNPK(qb, eB);
        if (t0 == 0) {   // exact init (c == 0, 1)
            m0 = (l == 0) ? eP0 : 0.f;
            m1 = 0.f; m2 = 0.f; m3 = 0.f; m4 = 0.f; m5 = 0.f; m6 = 0.f; m7 = 0.f;
        } else {
            m0 = eP0; m1 = eP1; m2 = eP2; m3 = eP3;
            m4 = eP4; m5 = eP5; m6 = eP6; m7 = eP7;
        }
        v0 = m0*eB0; v1 = m1*eB1; v2 = m2*eB2; v3 = m3*eB3;
        v4 = m4*eB4; v5 = m5*eB5; v6 = m6*eB6; v7 = m7*eB7;
    }
    u64 acc = 0ULL;
    const int cnt = tend - t0;          // 63/31
    const int ng = (cnt + 1) >> 3;      // 8/4
    VISSUE(0);
    VISSUE(1);
    VISSUE(2);
    int t = t0 + 1;
    int buf = 0;
    for (int g = 0; g < ng - 1; ++g) {
        WAITV(32);   // <=2 groups (16 loads each) outstanding -> group g arrived
        VSTEPD(t + 0, 0);  VSTEPD(t + 1, 1);  VSTEPD(t + 2, 2);  VSTEPD(t + 3, 3);
        VSTEPD(t + 4, 4);  VSTEPD(t + 5, 5);  VSTEPD(t + 6, 6);  VSTEPD(t + 7, 7);
        RENORM_MI();
        RENORM_VR();
        FENCE_LGKM();
        if (g + 3 < ng) VISSUE(g + 3);
        __builtin_amdgcn_sched_barrier(0);
        buf = (buf + 1) & 3;
        t += 8;
    }
    WAITV(0);
    VSTEPD(t + 0, 0);  VSTEPD(t + 1, 1);  VSTEPD(t + 2, 2);  VSTEPD(t + 3, 3);
    VSTEPD(t + 4, 4);  VSTEPD(t + 5, 5);  VSTEPD(t + 6, 6);

    float eex = (c == 31) ? __shfl(m7, 63) : __shfl(m0, 2 * (c + 1));
    if (l == 0) {
        elog[b * 32 + c] = __builtin_amdgcn_logf(fmaxf(eex, 1e-35f)) + (float)ioffM;
        if (c >= 1)
            wlg[b * 32 + c] = __builtin_amdgcn_logf(fmaxf(wex, 1e-35f)) + (float)wio;
    }
}

// ---------------------------------------------------------------------------
// K6a: per-(b,chunk) backtrace maps.
__global__ __launch_bounds__(512) void k_map(const u64* __restrict__ mbg,
                                             u16* __restrict__ map) {
    __shared__ u64 mb[4][64];   // 2 KB: taus 4c..4c+3
    const int b = blockIdx.x >> 5, c = blockIdx.x & 31;
    const int tid = threadIdx.x;
    const u64* src = mbg + (size_t)b * 8192 + (size_t)(4 * c) * 64;
    if (tid < 128) ((uint4*)&mb[0][0])[tid] = ((const uint4*)src)[tid];
    __syncthreads();
    int jj = tid;
    const int kmin = (c == 0) ? 1 : 0;
    for (int k = 31; k >= kmin; --k) {
        u64 word = mb[k >> 3][jj >> 3];
        jj -= (int)((word >> ((k & 7) * 8 + (jj & 7))) & 1ULL);
    }
    map[((size_t)b * 32 + c) * 512 + tid] = (u16)jj;
}

// K6b: compose maps then 32 lanes re-trace chunks in parallel.
__global__ __launch_bounds__(256) void k_btr2(const u64* __restrict__ mbg,
                                              const u16* __restrict__ map,
                                              int* __restrict__ js) {
    __shared__ u64 mb[128][64];   // 64 KB
    __shared__ u16 cent[32];
    const int b = blockIdx.x, tid = threadIdx.x;
    const uint4* src = (const uint4*)(mbg + (size_t)b * 8192);
    uint4* dst = (uint4*)&mb[0][0];
    for (int i = tid; i < 4096; i += 256) dst[i] = src[i];
    if (tid == 0) {
        int jj = 511;
        cent[31] = 511;
        for (int c = 31; c >= 1; --c) {
            jj = (int)map[((size_t)b * 32 + c) * 512 + jj];
            cent[c - 1] = (u16)jj;
        }
    }
    __syncthreads();
    if (tid < 32) {
        const int c = tid;
        int jj = (int)cent[c];
        js[b * T_ + 32 * c + 31] = jj;
        const int kmin = (c == 0) ? 1 : 0;
        for (int k = 31; k >= kmin; --k) {
            const int t = 32 * c + k;
            u64 word = mb[t >> 3][jj >> 3];
            jj -= (int)((word >> ((t & 7) * 8 + (jj & 7))) & 1ULL);
            js[b * T_ + t - 1] = jj;
        }
    }
}

// ---------------------------------------------------------------------------
// K7: fused one-hot path writer (blocks 0..4095) + logprobs (blocks 4096..4127).
__global__ __launch_bounds__(256) void k_out(const int* __restrict__ js,
                                             const u16* __restrict__ P,
                                             const float* __restrict__ lp_part,
                                             const int* __restrict__ tlen,
                                             const float* __restrict__ elog,
                                             const float* __restrict__ wlg,
                                             float* __restrict__ outp,
                                             float* __restrict__ out_lp) {
    if (blockIdx.x < 4096) {
        const size_t total4 = (size_t)B_ * T_ * S_ / 4;
        float4* O = (float4*)outp;
        for (size_t i = (size_t)blockIdx.x * 256 + threadIdx.x; i < total4;
             i += (size_t)4096 * 256) {
            size_t base = i * 4;
            int s = (int)(base & (S_ - 1));
            int row = (int)(base >> 9);
            int jt = js[row];
            float4 o;
            o.x = (s == jt) ? 1.f : 0.f;
            o.y = (s + 1 == jt) ? 1.f : 0.f;
            o.z = (s + 2 == jt) ? 1.f : 0.f;
            o.w = (s + 3 == jt) ? 1.f : 0.f;
            O[i] = o;
        }
    } else {
        const int b = blockIdx.x - 4096;
        float acc = 0.f;
        for (int t = threadIdx.x; t < T_; t += 256) {
            int jt = js[b * T_ + t];
            unsigned u = P[((size_t)b * T_ + t) * S_ + jt];
            acc += __builtin_amdgcn_logf(__uint_as_float(u << 16));
        }
        __shared__ float red[256];
        red[threadIdx.x] = acc;
        __syncthreads();
        for (int o = 128; o > 0; o >>= 1) {
            if (threadIdx.x < o) red[threadIdx.x] += red[threadIdx.x + o];
            __syncthreads();
        }
        if (threadIdx.x == 0) {
            float basep = 0.f;
            for (int i = 0; i < 48; ++i) basep += lp_part[b * 48 + i];
            float mu2n = elog[b * 32 + 31];
            for (int cc = 1; cc < 32; ++cc)
                mu2n += elog[b * 32 + cc - 1] - wlg[b * 32 + cc];
            out_lp[b] = basep - HALF_LOG_2PI * ((float)tlen[b] * C_)
                        + LN2F * (red[0] - mu2n);
        }
    }
}

// ---------------------------------------------------------------------------
extern "C" void kernel_launch(void* const* d_in, const int* in_sizes, int n_in,
                              void* d_out, int out_size, void* d_ws, size_t ws_size,
                              hipStream_t stream) {
    const float* eps  = (const float*)d_in[0];
    const float* cond = (const float*)d_in[1];
    const int* tlen   = (const int*)d_in[2];

    float* out_path = (float*)d_out;
    float* out_lp   = out_path + (size_t)B_ * T_ * S_;

    const size_t NBTS = (size_t)B_ * T_ * S_;
    char* w = (char*)d_ws;
    u16*   Wb   = (u16*)w;                            // 34 MB bf16 logits
    u16*   P    = Wb + NBTS;                          // 34 MB bf16 exp(W)/4
    u16*   Bt   = P + NBTS;                           // 34 MB bf16 linear beta
    u16*   Abf  = Bt + NBTS;                          // 25 MB bf16 eps
    u16*   Bbf  = Abf + (size_t)B_ * T_ * C_;         // 13 MB bf16 cond
    u64*   mbg  = (u64*)(Bbf + (size_t)B_ * S_ * C_); // 2 MB move bits
    float* pmax = (float*)(mbg + (size_t)B_ * 8192);
    float* psum = pmax + (size_t)4 * B_ * S_;
    float* cmax = psum + (size_t)4 * B_ * S_;
    float* cinv = cmax + (size_t)B_ * S_;
    float* lp_part = cinv + (size_t)B_ * S_;
    float* elog = lp_part + B_ * 48;                  // B*32
    float* wlg  = elog + B_ * 32;                     // B*32
    int*   js   = (int*)(wlg + B_ * 32);              // B*T
    u16*   map  = (u16*)(js + B_ * T_);               // 1 MB backtrace maps

    k_pre<<<2048, 256, 0, stream>>>(eps, cond, tlen, lp_part, Abf, Bbf);
    k_gemm<<<1024, 256, 0, stream>>>(Abf, Bbf, Wb);
    k_stats1<<<B_ * 4, 256, 0, stream>>>(Wb, pmax, psum);
    k_stats2<<<B_ * S_ / 256, 256, 0, stream>>>(pmax, psum, cmax, cinv);
    k_pack<<<2048, 256, 0, stream>>>(Wb, cmax, cinv, P);
    k_beta<<<B_ * 32, 64, 0, stream>>>(P, Bt);
    k_vit<<<B_ * 32, 64, 0, stream>>>(P, Bt, mbg, elog, wlg);
    k_map<<<B_ * 32, 512, 0, stream>>>(mbg, map);
    k_btr2<<<B_, 256, 0, stream>>>(mbg, map, js);
    k_out<<<4096 + B_, 256, 0, stream>>>(js, P, lp_part, tlen, elog, wlg,
                                         out_path, out_lp);
}

// Round 14
// 154.460 us; speedup vs baseline: 1.1657x; 1.0947x over previous
//
#include <hip/hip_runtime.h>
#include <cstdint>
#include <cstddef>

#define B_ 32
#define T_ 1024
#define S_ 512
#define C_ 384
#define HALF_LOG_2PI 0.91893853320467274178f
#define LN2F 0.69314718055994530942f
#define INV_LN2F 1.44269504088896340736f

typedef unsigned short u16;
typedef unsigned long long u64;
typedef __attribute__((ext_vector_type(8))) short bf16x8;
typedef __attribute__((ext_vector_type(4))) float f32x4;

__device__ __forceinline__ unsigned rne16(float f) {   // f32 -> bf16 bits (RNE)
    unsigned b = __float_as_uint(f);
    return (b + 0x7FFFu + ((b >> 16) & 1u)) >> 16;
}
__device__ __forceinline__ uint4 pack8f(float a0, float a1, float a2, float a3,
                                        float a4, float a5, float a6, float a7) {
    uint4 q;
    q.x = rne16(a0) | (rne16(a1) << 16);
    q.y = rne16(a2) | (rne16(a3) << 16);
    q.z = rne16(a4) | (rne16(a5) << 16);
    q.w = rne16(a6) | (rne16(a7) << 16);
    return q;
}
#define UNPK(q, p)                                                              \
    float p##0 = __uint_as_float((q).x << 16),                                  \
          p##1 = __uint_as_float((q).x & 0xFFFF0000u),                          \
          p##2 = __uint_as_float((q).y << 16),                                  \
          p##3 = __uint_as_float((q).y & 0xFFFF0000u),                          \
          p##4 = __uint_as_float((q).z << 16),                                  \
          p##5 = __uint_as_float((q).z & 0xFFFF0000u),                          \
          p##6 = __uint_as_float((q).w << 16),                                  \
          p##7 = __uint_as_float((q).w & 0xFFFF0000u)

#define PROW(t) (*(const uint4*)(Pb  + (size_t)(t) * S_ + l8))
#define BROW(t) (*(const uint4*)(Btb + (size_t)(t) * S_ + l8))

// ---------------------------------------------------------------------------
// DPP helpers: VALU-only cross-lane.
template <int CTRL>
__device__ __forceinline__ float fdpp0(float x) {     // invalid src lanes -> 0
    return __uint_as_float((unsigned)__builtin_amdgcn_update_dpp(
        0, (int)__float_as_uint(x), CTRL, 0xF, 0xF, true));
}
__device__ __forceinline__ float wave_fmax(float x) { // uniform full-wave max
    x = fmaxf(x, fdpp0<0x121>(x));   // row_ror:1
    x = fmaxf(x, fdpp0<0x122>(x));   // row_ror:2
    x = fmaxf(x, fdpp0<0x124>(x));   // row_ror:4
    x = fmaxf(x, fdpp0<0x128>(x));   // row_ror:8
    float a = __uint_as_float((unsigned)__builtin_amdgcn_readlane((int)__float_as_uint(x), 0));
    float b = __uint_as_float((unsigned)__builtin_amdgcn_readlane((int)__float_as_uint(x), 16));
    float c = __uint_as_float((unsigned)__builtin_amdgcn_readlane((int)__float_as_uint(x), 32));
    float d = __uint_as_float((unsigned)__builtin_amdgcn_readlane((int)__float_as_uint(x), 48));
    return fmaxf(fmaxf(a, b), fmaxf(c, d));
}

__device__ __forceinline__ void gll16(const u16* g, u16* l) {
    __builtin_amdgcn_global_load_lds(
        (const __attribute__((address_space(1))) void*)g,
        (__attribute__((address_space(3))) void*)l, 16, 0, 0);
}
#define WAITV(N) do { asm volatile("s_waitcnt vmcnt(" #N ")" ::: "memory");     \
                      __builtin_amdgcn_sched_barrier(0); } while (0)
#define FENCE_LGKM() do { asm volatile("s_waitcnt lgkmcnt(0)" ::: "memory");    \
                          __builtin_amdgcn_sched_barrier(0); } while (0)

// ---------------------------------------------------------------------------
// K0: fused eps->bf16 + eps^2 partials (blocks 0..1535) and cond->bf16 (rest).
__global__ __launch_bounds__(256) void k_pre(const float* __restrict__ eps,
                                             const float* __restrict__ cond,
                                             const int* __restrict__ tlen,
                                             float* __restrict__ lp_part,
                                             u16* __restrict__ Abf,
                                             u16* __restrict__ Bbf) {
    if (blockIdx.x < 1536) {
        const int b = blockIdx.x / 48, chunk = blockIdx.x % 48;
        const int len = tlen[b];
        const float* base = eps + (size_t)b * T_ * C_ + (size_t)chunk * 8192;
        u16* obase = Abf + (size_t)b * T_ * C_ + (size_t)chunk * 8192;
        float acc = 0.f;
        for (int g = threadIdx.x; g < 1024; g += 256) {
            float4 v0 = *(const float4*)(base + g * 8);
            float4 v1 = *(const float4*)(base + g * 8 + 4);
            int t = (chunk * 8192 + g * 8) / C_;
            if (t < len)
                acc += v0.x*v0.x + v0.y*v0.y + v0.z*v0.z + v0.w*v0.w
                     + v1.x*v1.x + v1.y*v1.y + v1.z*v1.z + v1.w*v1.w;
            *(uint4*)(obase + g * 8) = pack8f(v0.x, v0.y, v0.z, v0.w,
                                              v1.x, v1.y, v1.z, v1.w);
        }
        __shared__ float red[256];
        red[threadIdx.x] = acc;
        __syncthreads();
        for (int o = 128; o > 0; o >>= 1) {
            if (threadIdx.x < o) red[threadIdx.x] += red[threadIdx.x + o];
            __syncthreads();
        }
        if (threadIdx.x == 0) lp_part[blockIdx.x] = -0.5f * red[0];
    } else {
        const size_t n8 = (size_t)B_ * S_ * C_ / 8;
        for (size_t i = (size_t)(blockIdx.x - 1536) * 256 + threadIdx.x; i < n8;
             i += (size_t)512 * 256) {
            float4 v0 = *(const float4*)(cond + i * 8);
            float4 v1 = *(const float4*)(cond + i * 8 + 4);
            *(uint4*)(Bbf + i * 8) = pack8f(v0.x, v0.y, v0.z, v0.w,
                                            v1.x, v1.y, v1.z, v1.w);
        }
    }
}

// ---------------------------------------------------------------------------
// K1: bf16 MFMA GEMM -> bf16 logits Wb. 128x128 tile, 4 waves, BK=32.
// 1-D grid, XCD-swizzled: all 32 tiles of a batch land on one XCD.
__global__ __launch_bounds__(256) void k_gemm(const u16* __restrict__ A,
                                              const u16* __restrict__ Bc,
                                              u16* __restrict__ Wb) {
    __shared__ u16 Al[4096];
    __shared__ u16 Bl[4096];
    const int wgid = blockIdx.x;
    const int xcd  = wgid & 7;
    const int rest = wgid >> 3;            // 0..127
    const int b    = (rest >> 5) * 8 + xcd;
    const int tile = rest & 31;            // 0..31 = (m,n) tile
    const int m0 = (tile >> 2) * 128;
    const int n0 = (tile & 3) * 128;
    const int tid = threadIdx.x;
    const int lane = tid & 63, wid = tid >> 6;
    const int wy = wid >> 1, wx = wid & 1;
    const int r15 = lane & 15, kg = lane >> 4;
    const u16* Ab = A  + (size_t)b * T_ * C_;
    const u16* Bb = Bc + (size_t)b * S_ * C_;

    f32x4 acc[4][4];
#pragma unroll
    for (int i = 0; i < 4; ++i)
#pragma unroll
        for (int j = 0; j < 4; ++j) acc[i][j] = (f32x4){0.f, 0.f, 0.f, 0.f};

    const int row0 = tid >> 2, o0 = tid & 3;
    const int row1 = row0 + 64;
    const int wb0 = (row0 * 64 + o0 * 16) ^ (((row0 >> 1) & 7) << 4);
    const int wb1 = (row1 * 64 + o0 * 16) ^ (((row1 >> 1) & 7) << 4);
    const int rswz = ((r15 >> 1) & 7) << 4;

    for (int k0 = 0; k0 < C_; k0 += 32) {
        uint4 a0 = *(const uint4*)(Ab + (size_t)(m0 + row0) * C_ + k0 + o0 * 8);
        uint4 a1 = *(const uint4*)(Ab + (size_t)(m0 + row1) * C_ + k0 + o0 * 8);
        uint4 c0 = *(const uint4*)(Bb + (size_t)(n0 + row0) * C_ + k0 + o0 * 8);
        uint4 c1 = *(const uint4*)(Bb + (size_t)(n0 + row1) * C_ + k0 + o0 * 8);
        __syncthreads();
        *(uint4*)((char*)Al + wb0) = a0;
        *(uint4*)((char*)Al + wb1) = a1;
        *(uint4*)((char*)Bl + wb0) = c0;
        *(uint4*)((char*)Bl + wb1) = c1;
        __syncthreads();
        bf16x8 af[4], bfb[4];
#pragma unroll
        for (int ar = 0; ar < 4; ++ar) {
            int row = wy * 64 + ar * 16 + r15;
            af[ar] = *(const bf16x8*)((const char*)Al + ((row * 64 + kg * 16) ^ rswz));
        }
#pragma unroll
        for (int bc = 0; bc < 4; ++bc) {
            int row = wx * 64 + bc * 16 + r15;
            bfb[bc] = *(const bf16x8*)((const char*)Bl + ((row * 64 + kg * 16) ^ rswz));
        }
#pragma unroll
        for (int ar = 0; ar < 4; ++ar)
#pragma unroll
            for (int bc = 0; bc < 4; ++bc)
                acc[ar][bc] = __builtin_amdgcn_mfma_f32_16x16x32_bf16(
                    af[ar], bfb[bc], acc[ar][bc], 0, 0, 0);
    }
#pragma unroll
    for (int ar = 0; ar < 4; ++ar) {
        int t = m0 + wy * 64 + ar * 16 + kg * 4;
#pragma unroll
        for (int bc = 0; bc < 4; ++bc) {
            int s = n0 + wx * 64 + bc * 16 + r15;
            u16* dst = Wb + ((size_t)b * T_ + t) * S_ + s;
#pragma unroll
            for (int r = 0; r < 4; ++r) dst[(size_t)r * S_] = (u16)rne16(acc[ar][bc][r]);
        }
    }
}

// ---------------------------------------------------------------------------
// K2a: column stats over 256-row chunk. 4 waves, 8 cols/lane, uint4 row loads.
#define COLU(i, xa, xb, xc, xd) do {                                            \
    float nm = fmaxf(fmaxf(fmaxf(m[i], xa), xb), fmaxf(xc, xd));                \
    s[i] = s[i] * __builtin_amdgcn_exp2f((m[i] - nm) * INV_LN2F)                \
         + __builtin_amdgcn_exp2f((xa - nm) * INV_LN2F)                         \
         + __builtin_amdgcn_exp2f((xb - nm) * INV_LN2F)                         \
         + __builtin_amdgcn_exp2f((xc - nm) * INV_LN2F)                         \
         + __builtin_amdgcn_exp2f((xd - nm) * INV_LN2F);                        \
    m[i] = nm;                                                                  \
} while (0)

__global__ __launch_bounds__(256) void k_stats1(const u16* __restrict__ Wb,
                                                float* __restrict__ pmax,
                                                float* __restrict__ psum) {
    __shared__ float smax[4][S_];
    __shared__ float ssum[4][S_];
    const int c = blockIdx.x & 3;
    const int b = blockIdx.x >> 2;
    const int w = threadIdx.x >> 6, l = threadIdx.x & 63;
    const u16* base = Wb + (size_t)b * T_ * S_ + (size_t)(c * 256 + w * 64) * S_ + l * 8;
    float m[8], s[8];
#pragma unroll
    for (int i = 0; i < 8; ++i) { m[i] = -3.0e38f; s[i] = 0.f; }
    for (int t = 0; t < 64; t += 4) {
        uint4 q0 = *(const uint4*)(base + (size_t)(t + 0) * S_);
        uint4 q1 = *(const uint4*)(base + (size_t)(t + 1) * S_);
        uint4 q2 = *(const uint4*)(base + (size_t)(t + 2) * S_);
        uint4 q3 = *(const uint4*)(base + (size_t)(t + 3) * S_);
        UNPK(q0, xa); UNPK(q1, xb); UNPK(q2, xc); UNPK(q3, xd);
        COLU(0, xa0, xb0, xc0, xd0);
        COLU(1, xa1, xb1, xc1, xd1);
        COLU(2, xa2, xb2, xc2, xd2);
        COLU(3, xa3, xb3, xc3, xd3);
        COLU(4, xa4, xb4, xc4, xd4);
        COLU(5, xa5, xb5, xc5, xd5);
        COLU(6, xa6, xb6, xc6, xd6);
        COLU(7, xa7, xb7, xc7, xd7);
    }
#pragma unroll
    for (int i = 0; i < 8; ++i) {
        smax[w][l * 8 + i] = m[i];
        ssum[w][l * 8 + i] = s[i];
    }
    __syncthreads();
    for (int col = threadIdx.x; col < S_; col += 256) {
        float m0 = smax[0][col], m1 = smax[1][col];
        float m2 = smax[2][col], m3 = smax[3][col];
        float nm = fmaxf(fmaxf(m0, m1), fmaxf(m2, m3));
        float ss = ssum[0][col] * __builtin_amdgcn_exp2f((m0 - nm) * INV_LN2F)
                 + ssum[1][col] * __builtin_amdgcn_exp2f((m1 - nm) * INV_LN2F)
                 + ssum[2][col] * __builtin_amdgcn_exp2f((m2 - nm) * INV_LN2F)
                 + ssum[3][col] * __builtin_amdgcn_exp2f((m3 - nm) * INV_LN2F);
        pmax[(size_t)c * B_ * S_ + b * S_ + col] = nm;
        psum[(size_t)c * B_ * S_ + b * S_ + col] = ss;
    }
}

__global__ __launch_bounds__(256) void k_stats2(const float* __restrict__ pmax,
                                                const float* __restrict__ psum,
                                                float* __restrict__ cmax,
                                                float* __restrict__ cinv) {
    const int i = blockIdx.x * 256 + threadIdx.x;
    float m0 = pmax[i], m1 = pmax[(size_t)B_ * S_ + i];
    float m2 = pmax[(size_t)2 * B_ * S_ + i], m3 = pmax[(size_t)3 * B_ * S_ + i];
    float m = fmaxf(fmaxf(m0, m1), fmaxf(m2, m3));
    float s = psum[i] * expf(m0 - m)
            + psum[(size_t)B_ * S_ + i] * expf(m1 - m)
            + psum[(size_t)2 * B_ * S_ + i] * expf(m2 - m)
            + psum[(size_t)3 * B_ * S_ + i] * expf(m3 - m);
    cmax[i] = m;
    cinv[i] = 1.0f / s;
}

// ---------------------------------------------------------------------------
// K3: P_hat = exp(softmax(Wb,axis=T)) / 4, bf16.
__global__ __launch_bounds__(256) void k_pack(const u16* __restrict__ Wb,
                                              const float* __restrict__ cmax,
                                              const float* __restrict__ cinv,
                                              u16* __restrict__ P) {
    const size_t total8 = (size_t)B_ * T_ * S_ / 8;
    for (size_t i = (size_t)blockIdx.x * 256 + threadIdx.x; i < total8;
         i += (size_t)gridDim.x * 256) {
        size_t base = i * 8;
        int s = (int)(base & (S_ - 1));
        int b = (int)(base >> 19);
        uint4 xq = *(const uint4*)(Wb + base);
        UNPK(xq, x);
        float4 mA = *(const float4*)(cmax + (size_t)b * S_ + s);
        float4 mB = *(const float4*)(cmax + (size_t)b * S_ + s + 4);
        float4 iA = *(const float4*)(cinv + (size_t)b * S_ + s);
        float4 iB = *(const float4*)(cinv + (size_t)b * S_ + s + 4);
        float w0 = __builtin_amdgcn_exp2f(fmaf(x0, INV_LN2F, -mA.x * INV_LN2F)) * iA.x;
        float w1 = __builtin_amdgcn_exp2f(fmaf(x1, INV_LN2F, -mA.y * INV_LN2F)) * iA.y;
        float w2 = __builtin_amdgcn_exp2f(fmaf(x2, INV_LN2F, -mA.z * INV_LN2F)) * iA.z;
        float w3 = __builtin_amdgcn_exp2f(fmaf(x3, INV_LN2F, -mA.w * INV_LN2F)) * iA.w;
        float w4 = __builtin_amdgcn_exp2f(fmaf(x4, INV_LN2F, -mB.x * INV_LN2F)) * iB.x;
        float w5 = __builtin_amdgcn_exp2f(fmaf(x5, INV_LN2F, -mB.y * INV_LN2F)) * iB.y;
        float w6 = __builtin_amdgcn_exp2f(fmaf(x6, INV_LN2F, -mB.z * INV_LN2F)) * iB.z;
        float w7 = __builtin_amdgcn_exp2f(fmaf(x7, INV_LN2F, -mB.w * INV_LN2F)) * iB.w;
        float p0 = __builtin_amdgcn_exp2f(fmaf(w0, INV_LN2F, -2.0f));
        float p1 = __builtin_amdgcn_exp2f(fmaf(w1, INV_LN2F, -2.0f));
        float p2 = __builtin_amdgcn_exp2f(fmaf(w2, INV_LN2F, -2.0f));
        float p3 = __builtin_amdgcn_exp2f(fmaf(w3, INV_LN2F, -2.0f));
        float p4 = __builtin_amdgcn_exp2f(fmaf(w4, INV_LN2F, -2.0f));
        float p5 = __builtin_amdgcn_exp2f(fmaf(w5, INV_LN2F, -2.0f));
        float p6 = __builtin_amdgcn_exp2f(fmaf(w6, INV_LN2F, -2.0f));
        float p7 = __builtin_amdgcn_exp2f(fmaf(w7, INV_LN2F, -2.0f));
        *(uint4*)(P + base) = pack8f(p0, p1, p2, p3, p4, p5, p6, p7);
    }
}

// ---------------------------------------------------------------------------
// K4: backward DP, linear domain. 32 chunks of 32 + 32-step warm-up, GROUP=8
// 2-deep LDS double-buffer, vmcnt pipeline, DPP shift, XCD co-location.
#define RENORM_B() do {                                                         \
    float mx_ = wave_fmax(fmaxf(fmaxf(fmaxf(m0,m1),fmaxf(m2,m3)),               \
                                fmaxf(fmaxf(m4,m5),fmaxf(m6,m7))));             \
    int eb_ = (__float_as_int(mx_) >> 23) & 255;                                \
    float sc_ = (eb_ > 0) ? __int_as_float((254 - eb_) << 23) : 1.0f;           \
    m0*=sc_; m1*=sc_; m2*=sc_; m3*=sc_; m4*=sc_; m5*=sc_; m6*=sc_; m7*=sc_;     \
} while (0)

#define BSTEPD(tt, jj) do {                                                     \
    uint4 q_ = *(const uint4*)&Pl[buf][jj][l8];                                 \
    UNPK(q_, eP);                                                               \
    float z0=m0*eP0, z1=m1*eP1, z2=m2*eP2, z3=m3*eP3;                           \
    float z4=m4*eP4, z5=m5*eP5, z6=m6*eP6, z7=m7*eP7;                           \
    float rt = fdpp0<0x130>(z0);  /* lane l <- l+1, lane63 -> 0 */              \
    m0=z0+z1; m1=z1+z2; m2=z2+z3; m3=z3+z4;                                     \
    m4=z4+z5; m5=z5+z6; m6=z6+z7; m7=z7+rt;                                     \
    if ((tt) < w0 + 32) {                                                       \
        uint4 st;                                                               \
        asm("v_cvt_pk_bf16_f32 %0, %1, %2" : "=v"(st.x) : "v"(m0), "v"(m1));    \
        asm("v_cvt_pk_bf16_f32 %0, %1, %2" : "=v"(st.y) : "v"(m2), "v"(m3));    \
        asm("v_cvt_pk_bf16_f32 %0, %1, %2" : "=v"(st.z) : "v"(m4), "v"(m5));    \
        asm("v_cvt_pk_bf16_f32 %0, %1, %2" : "=v"(st.w) : "v"(m6), "v"(m7));    \
        *(uint4*)(Bb + (size_t)(tt) * S_ + l8) = st;                            \
    }                                                                           \
} while (0)

__global__ __launch_bounds__(64) void k_beta(const u16* __restrict__ P,
                                             u16* __restrict__ Bt) {
    __shared__ u16 Pl[2][8][S_];        // 16 KB
    const int l = threadIdx.x, l8 = l * 8;
    const int xcd = blockIdx.x & 7;
    const int idx = blockIdx.x >> 3;
    const int c = idx & 31;
    const int b = ((idx >> 5) << 3) + xcd;   // all chunks of b on one XCD
    const int w0 = c * 32;
    const u16* Pb = P  + (size_t)b * T_ * S_;
    u16*      Bb = Bt + (size_t)b * T_ * S_;
    float m0, m1, m2, m3, m4, m5, m6, m7;
    int te = w0 + 63;
    if (te > 1023) te = 1023;
    if (te == 1023) {    // exact init (c == 30, 31)
        m0 = m1 = m2 = m3 = m4 = m5 = m6 = 0.f;
        m7 = (l == 63) ? 1.f : 0.f;
        if (1023 < w0 + 32) {   // c == 31 stores init row
            uint4 st;
            asm("v_cvt_pk_bf16_f32 %0, %1, %2" : "=v"(st.x) : "v"(m0), "v"(m1));
            asm("v_cvt_pk_bf16_f32 %0, %1, %2" : "=v"(st.y) : "v"(m2), "v"(m3));
            asm("v_cvt_pk_bf16_f32 %0, %1, %2" : "=v"(st.z) : "v"(m4), "v"(m5));
            asm("v_cvt_pk_bf16_f32 %0, %1, %2" : "=v"(st.w) : "v"(m6), "v"(m7));
            *(uint4*)(Bb + (size_t)1023 * S_ + l8) = st;
        }
    } else {
        m0 = m1 = m2 = m3 = m4 = m5 = m6 = m7 = 1.f;
    }
    const int cnt = te - w0;            // 63/31, == 7 mod 8
    const int ng = (cnt + 1) >> 3;      // 8/4
#pragma unroll
    for (int r = 0; r < 8; ++r)
        gll16(Pb + (size_t)(te - r) * S_ + l8, &Pl[0][r][0]);
#pragma unroll
    for (int r = 0; r < 8; ++r)
        gll16(Pb + (size_t)(te - 8 - r) * S_ + l8, &Pl[1][r][0]);
    int tt = te - 1;
    int buf = 0;
    for (int g = 0; g < ng - 1; ++g) {
        WAITV(8);
        BSTEPD(tt - 0, 0);  BSTEPD(tt - 1, 1);  BSTEPD(tt - 2, 2);  BSTEPD(tt - 3, 3);
        BSTEPD(tt - 4, 4);  BSTEPD(tt - 5, 5);  BSTEPD(tt - 6, 6);  BSTEPD(tt - 7, 7);
        RENORM_B();
        FENCE_LGKM();
        if (g + 2 < ng) {
            const int bs = te - 8 * (g + 2);
#pragma unroll
            for (int r = 0; r < 8; ++r)
                gll16(Pb + (size_t)(bs - r) * S_ + l8, &Pl[buf][r][0]);
        }
        __builtin_amdgcn_sched_barrier(0);
        buf ^= 1;
        tt -= 8;
    }
    WAITV(0);
    BSTEPD(tt - 0, 0);  BSTEPD(tt - 1, 1);  BSTEPD(tt - 2, 2);  BSTEPD(tt - 3, 3);
    BSTEPD(tt - 4, 4);  BSTEPD(tt - 5, 5);  BSTEPD(tt - 6, 6);
}

// ---------------------------------------------------------------------------
// K5: fused mu-forward + Viterbi, linear domain, 32 chunks of 32, 32 warm-up,
// 2-deep LDS double-buffer on both streams.
#define RENORM_MI() do {                                                        \
    float mx_ = wave_fmax(fmaxf(fmaxf(fmaxf(m0,m1),fmaxf(m2,m3)),               \
                                fmaxf(fmaxf(m4,m5),fmaxf(m6,m7))));             \
    int eb_ = (__float_as_int(mx_) >> 23) & 255;                                \
    float sc_ = (eb_ > 0) ? __int_as_float((254 - eb_) << 23) : 1.0f;           \
    if (eb_ > 0) ioffM += eb_ - 127;                                            \
    m0*=sc_; m1*=sc_; m2*=sc_; m3*=sc_; m4*=sc_; m5*=sc_; m6*=sc_; m7*=sc_;     \
} while (0)

#define RENORM_VR() do {                                                        \
    float mx_ = wave_fmax(fmaxf(fmaxf(fmaxf(v0,v1),fmaxf(v2,v3)),               \
                                fmaxf(fmaxf(v4,v5),fmaxf(v6,v7))));             \
    int eb_ = (__float_as_int(mx_) >> 23) & 255;                                \
    float sc_ = (eb_ > 0) ? __int_as_float((254 - eb_) << 23) : 0.0f;           \
    float ad_ = (eb_ > 0) ? 0.f : 1.f;                                          \
    v0=fmaf(v0,sc_,ad_); v1=fmaf(v1,sc_,ad_); v2=fmaf(v2,sc_,ad_);              \
    v3=fmaf(v3,sc_,ad_); v4=fmaf(v4,sc_,ad_); v5=fmaf(v5,sc_,ad_);              \
    v6=fmaf(v6,sc_,ad_); v7=fmaf(v7,sc_,ad_);                                   \
} while (0)

#define VSTEPD(TT, jj) do {                                                     \
    uint4 qp_ = *(const uint4*)&Pl[buf][jj][l8];                                \
    uint4 qb_ = *(const uint4*)&Bl[buf][jj][l8];                                \
    UNPK(qp_, eP); UNPK(qb_, eB);                                               \
    float lf = fdpp0<0x138>(m7);  /* lane l <- l-1, lane0 -> 0 */               \
    float n0 = eP0*(m0+lf), n1 = eP1*(m1+m0);                                   \
    float n2 = eP2*(m2+m1), n3 = eP3*(m3+m2);                                   \
    float n4 = eP4*(m4+m3), n5 = eP5*(m5+m4);                                   \
    float n6 = eP6*(m6+m5), n7 = eP7*(m7+m6);                                   \
    float vlf = fdpp0<0x138>(v7);                                               \
    if ((TT) >= w0) {                                                           \
        unsigned cc0=(vlf>v0)?1u:0u, cc1=(v0>v1)?2u:0u, cc2=(v1>v2)?4u:0u,      \
                 cc3=(v2>v3)?8u:0u,  cc4=(v3>v4)?16u:0u, cc5=(v4>v5)?32u:0u,    \
                 cc6=(v5>v6)?64u:0u, cc7=(v6>v7)?128u:0u;                       \
        acc |= ((u64)(cc0|cc1|cc2|cc3|cc4|cc5|cc6|cc7)) << (((TT)&7)*8);        \
        if (((TT)&7) == 7) { mrow[((TT)>>3)*64 + l] = acc; acc = 0ULL; }        \
    }                                                                           \
    float w0v=(n0*eB0)*fmaxf(v0,vlf), w1v=(n1*eB1)*fmaxf(v1,v0);                \
    float w2v=(n2*eB2)*fmaxf(v2,v1),  w3v=(n3*eB3)*fmaxf(v3,v2);                \
    float w4v=(n4*eB4)*fmaxf(v4,v3),  w5v=(n5*eB5)*fmaxf(v5,v4);                \
    float w6v=(n6*eB6)*fmaxf(v6,v5),  w7v=(n7*eB7)*fmaxf(v7,v6);                \
    m0=n0;m1=n1;m2=n2;m3=n3;m4=n4;m5=n5;m6=n6;m7=n7;                            \
    v0=w0v;v1=w1v;v2=w2v;v3=w3v;v4=w4v;v5=w5v;v6=w6v;v7=w7v;                    \
    if ((TT) == wexp) { wex = __shfl(m0, 2 * c); wio = ioffM; }                 \
} while (0)

__global__ __launch_bounds__(64) void k_vit(const u16* __restrict__ P,
                                            const u16* __restrict__ Bt,
                                            u64* __restrict__ mbg,
                                            float* __restrict__ elog,
                                            float* __restrict__ wlg) {
    __shared__ u16 Pl[2][8][S_];        // 16 KB
    __shared__ u16 Bl[2][8][S_];        // 16 KB
    const int l = threadIdx.x, l8 = l * 8;
    const int xcd = blockIdx.x & 7;
    const int idx = blockIdx.x >> 3;
    const int c = idx & 31;
    const int b = ((idx >> 5) << 3) + xcd;
    const int w0 = c * 32, tend = w0 + 31;
    const int t0 = (w0 >= 32) ? (w0 - 32) : 0;
    const int wexp = w0 - 1;
    const u16* Pb  = P  + (size_t)b * T_ * S_;
    const u16* Btb = Bt + (size_t)b * T_ * S_;
    u64* mrow = mbg + (size_t)b * 8192;

    float m0,m1,m2,m3,m4,m5,m6,m7, v0,v1,v2,v3,v4,v5,v6,v7;
    int ioffM = 0;
    float wex = 1.f; int wio = 0;
    {
        uint4 qp = PROW(t0); UNPK(qp, eP);
        uint4 qb = BROW(t0); UNPK(qb, eB);
        if (t0 == 0) {   // exact init (c == 0, 1)
            m0 = (l == 0) ? eP0 : 0.f;
            m1 = 0.f; m2 = 0.f; m3 = 0.f; m4 = 0.f; m5 = 0.f; m6 = 0.f; m7 = 0.f;
        } else {
            m0 = eP0; m1 = eP1; m2 = eP2; m3 = eP3;
            m4 = eP4; m5 = eP5; m6 = eP6; m7 = eP7;
        }
        v0 = m0*eB0; v1 = m1*eB1; v2 = m2*eB2; v3 = m3*eB3;
        v4 = m4*eB4; v5 = m5*eB5; v6 = m6*eB6; v7 = m7*eB7;
    }
    u64 acc = 0ULL;
    const int cnt = tend - t0;          // 63/31
    const int ng = (cnt + 1) >> 3;      // 8/4
#pragma unroll
    for (int r = 0; r < 8; ++r) {
        gll16(Pb  + (size_t)(t0 + 1 + r) * S_ + l8, &Pl[0][r][0]);
        gll16(Btb + (size_t)(t0 + 1 + r) * S_ + l8, &Bl[0][r][0]);
    }
#pragma unroll
    for (int r = 0; r < 8; ++r) {
        gll16(Pb  + (size_t)(t0 + 9 + r) * S_ + l8, &Pl[1][r][0]);
        gll16(Btb + (size_t)(t0 + 9 + r) * S_ + l8, &Bl[1][r][0]);
    }
    int t = t0 + 1;
    int buf = 0;
    for (int g = 0; g < ng - 1; ++g) {
        WAITV(16);
        VSTEPD(t + 0, 0);  VSTEPD(t + 1, 1);  VSTEPD(t + 2, 2);  VSTEPD(t + 3, 3);
        VSTEPD(t + 4, 4);  VSTEPD(t + 5, 5);  VSTEPD(t + 6, 6);  VSTEPD(t + 7, 7);
        RENORM_MI();
        RENORM_VR();
        FENCE_LGKM();
        if (g + 2 < ng) {
            const int bs = t0 + 1 + 8 * (g + 2);
#pragma unroll
            for (int r = 0; r < 8; ++r) {
                gll16(Pb  + (size_t)(bs + r) * S_ + l8, &Pl[buf][r][0]);
                gll16(Btb + (size_t)(bs + r) * S_ + l8, &Bl[buf][r][0]);
            }
        }
        __builtin_amdgcn_sched_barrier(0);
        buf ^= 1;
        t += 8;
    }
    WAITV(0);
    VSTEPD(t + 0, 0);  VSTEPD(t + 1, 1);  VSTEPD(t + 2, 2);  VSTEPD(t + 3, 3);
    VSTEPD(t + 4, 4);  VSTEPD(t + 5, 5);  VSTEPD(t + 6, 6);

    float eex = (c == 31) ? __shfl(m7, 63) : __shfl(m0, 2 * (c + 1));
    if (l == 0) {
        elog[b * 32 + c] = __builtin_amdgcn_logf(fmaxf(eex, 1e-35f)) + (float)ioffM;
        if (c >= 1)
            wlg[b * 32 + c] = __builtin_amdgcn_logf(fmaxf(wex, 1e-35f)) + (float)wio;
    }
}

// ---------------------------------------------------------------------------
// K6a: per-(b,chunk) backtrace maps.
__global__ __launch_bounds__(512) void k_map(const u64* __restrict__ mbg,
                                             u16* __restrict__ map) {
    __shared__ u64 mb[4][64];   // 2 KB: taus 4c..4c+3
    const int b = blockIdx.x >> 5, c = blockIdx.x & 31;
    const int tid = threadIdx.x;
    const u64* src = mbg + (size_t)b * 8192 + (size_t)(4 * c) * 64;
    if (tid < 128) ((uint4*)&mb[0][0])[tid] = ((const uint4*)src)[tid];
    __syncthreads();
    int jj = tid;
    const int kmin = (c == 0) ? 1 : 0;
    for (int k = 31; k >= kmin; --k) {
        u64 word = mb[k >> 3][jj >> 3];
        jj -= (int)((word >> ((k & 7) * 8 + (jj & 7))) & 1ULL);
    }
    map[((size_t)b * 32 + c) * 512 + tid] = (u16)jj;
}

// K6b: compose maps then 32 lanes re-trace chunks in parallel.
__global__ __launch_bounds__(256) void k_btr2(const u64* __restrict__ mbg,
                                              const u16* __restrict__ map,
                                              int* __restrict__ js) {
    __shared__ u64 mb[128][64];   // 64 KB
    __shared__ u16 cent[32];
    const int b = blockIdx.x, tid = threadIdx.x;
    const uint4* src = (const uint4*)(mbg + (size_t)b * 8192);
    uint4* dst = (uint4*)&mb[0][0];
    for (int i = tid; i < 4096; i += 256) dst[i] = src[i];
    if (tid == 0) {
        int jj = 511;
        cent[31] = 511;
        for (int c = 31; c >= 1; --c) {
            jj = (int)map[((size_t)b * 32 + c) * 512 + jj];
            cent[c - 1] = (u16)jj;
        }
    }
    __syncthreads();
    if (tid < 32) {
        const int c = tid;
        int jj = (int)cent[c];
        js[b * T_ + 32 * c + 31] = jj;
        const int kmin = (c == 0) ? 1 : 0;
        for (int k = 31; k >= kmin; --k) {
            const int t = 32 * c + k;
            u64 word = mb[t >> 3][jj >> 3];
            jj -= (int)((word >> ((t & 7) * 8 + (jj & 7))) & 1ULL);
            js[b * T_ + t - 1] = jj;
        }
    }
}

// ---------------------------------------------------------------------------
// K7: fused one-hot path writer (blocks 0..4095) + logprobs (blocks 4096..4127).
__global__ __launch_bounds__(256) void k_out(const int* __restrict__ js,
                                             const u16* __restrict__ P,
                                             const float* __restrict__ lp_part,
                                             const int* __restrict__ tlen,
                                             const float* __restrict__ elog,
                                             const float* __restrict__ wlg,
                                             float* __restrict__ outp,
                                             float* __restrict__ out_lp) {
    if (blockIdx.x < 4096) {
        const size_t total4 = (size_t)B_ * T_ * S_ / 4;
        float4* O = (float4*)outp;
        for (size_t i = (size_t)blockIdx.x * 256 + threadIdx.x; i < total4;
             i += (size_t)4096 * 256) {
            size_t base = i * 4;
            int s = (int)(base & (S_ - 1));
            int row = (int)(base >> 9);
            int jt = js[row];
            float4 o;
            o.x = (s == jt) ? 1.f : 0.f;
            o.y = (s + 1 == jt) ? 1.f : 0.f;
            o.z = (s + 2 == jt) ? 1.f : 0.f;
            o.w = (s + 3 == jt) ? 1.f : 0.f;
            O[i] = o;
        }
    } else {
        const int b = blockIdx.x - 4096;
        float acc = 0.f;
        for (int t = threadIdx.x; t < T_; t += 256) {
            int jt = js[b * T_ + t];
            unsigned u = P[((size_t)b * T_ + t) * S_ + jt];
            acc += __builtin_amdgcn_logf(__uint_as_float(u << 16));
        }
        __shared__ float red[256];
        red[threadIdx.x] = acc;
        __syncthreads();
        for (int o = 128; o > 0; o >>= 1) {
            if (threadIdx.x < o) red[threadIdx.x] += red[threadIdx.x + o];
            __syncthreads();
        }
        if (threadIdx.x == 0) {
            float basep = 0.f;
            for (int i = 0; i < 48; ++i) basep += lp_part[b * 48 + i];
            float mu2n = elog[b * 32 + 31];
            for (int cc = 1; cc < 32; ++cc)
                mu2n += elog[b * 32 + cc - 1] - wlg[b * 32 + cc];
            out_lp[b] = basep - HALF_LOG_2PI * ((float)tlen[b] * C_)
                        + LN2F * (red[0] - mu2n);
        }
    }
}

// ---------------------------------------------------------------------------
extern "C" void kernel_launch(void* const* d_in, const int* in_sizes, int n_in,
                              void* d_out, int out_size, void* d_ws, size_t ws_size,
                              hipStream_t stream) {
    const float* eps  = (const float*)d_in[0];
    const float* cond = (const float*)d_in[1];
    const int* tlen   = (const int*)d_in[2];

    float* out_path = (float*)d_out;
    float* out_lp   = out_path + (size_t)B_ * T_ * S_;

    const size_t NBTS = (size_t)B_ * T_ * S_;
    char* w = (char*)d_ws;
    u16*   Wb   = (u16*)w;                            // 34 MB bf16 logits
    u16*   P    = Wb + NBTS;                          // 34 MB bf16 exp(W)/4
    u16*   Bt   = P + NBTS;                           // 34 MB bf16 linear beta
    u16*   Abf  = Bt + NBTS;                          // 25 MB bf16 eps
    u16*   Bbf  = Abf + (size_t)B_ * T_ * C_;         // 13 MB bf16 cond
    u64*   mbg  = (u64*)(Bbf + (size_t)B_ * S_ * C_); // 2 MB move bits
    float* pmax = (float*)(mbg + (size_t)B_ * 8192);
    float* psum = pmax + (size_t)4 * B_ * S_;
    float* cmax = psum + (size_t)4 * B_ * S_;
    float* cinv = cmax + (size_t)B_ * S_;
    float* lp_part = cinv + (size_t)B_ * S_;
    float* elog = lp_part + B_ * 48;                  // B*32
    float* wlg  = elog + B_ * 32;                     // B*32
    int*   js   = (int*)(wlg + B_ * 32);              // B*T
    u16*   map  = (u16*)(js + B_ * T_);               // 1 MB backtrace maps

    k_pre<<<2048, 256, 0, stream>>>(eps, cond, tlen, lp_part, Abf, Bbf);
    k_gemm<<<1024, 256, 0, stream>>>(Abf, Bbf, Wb);
    k_stats1<<<B_ * 4, 256, 0, stream>>>(Wb, pmax, psum);
    k_stats2<<<B_ * S_ / 256, 256, 0, stream>>>(pmax, psum, cmax, cinv);
    k_pack<<<2048, 256, 0, stream>>>(Wb, cmax, cinv, P);
    k_beta<<<B_ * 32, 64, 0, stream>>>(P, Bt);
    k_vit<<<B_ * 32, 64, 0, stream>>>(P, Bt, mbg, elog, wlg);
    k_map<<<B_ * 32, 512, 0, stream>>>(mbg, map);
    k_btr2<<<B_, 256, 0, stream>>>(mbg, map, js);
    k_out<<<4096 + B_, 256, 0, stream>>>(js, P, lp_part, tlen, elog, wlg,
                                         out_path, out_lp);
}

// Round 15
// 147.792 us; speedup vs baseline: 1.2183x; 1.0451x over previous
//
#include <hip/hip_runtime.h>
#include <cstdint>
#include <cstddef>

#define B_ 32
#define T_ 1024
#define S_ 512
#define C_ 384
#define HALF_LOG_2PI 0.91893853320467274178f
#define LN2F 0.69314718055994530942f
#define INV_LN2F 1.44269504088896340736f

typedef unsigned short u16;
typedef unsigned long long u64;
typedef __attribute__((ext_vector_type(8))) short bf16x8;
typedef __attribute__((ext_vector_type(4))) float f32x4;

__device__ __forceinline__ unsigned rne16(float f) {   // f32 -> bf16 bits (RNE)
    unsigned b = __float_as_uint(f);
    return (b + 0x7FFFu + ((b >> 16) & 1u)) >> 16;
}
__device__ __forceinline__ uint4 pack8f(float a0, float a1, float a2, float a3,
                                        float a4, float a5, float a6, float a7) {
    uint4 q;
    q.x = rne16(a0) | (rne16(a1) << 16);
    q.y = rne16(a2) | (rne16(a3) << 16);
    q.z = rne16(a4) | (rne16(a5) << 16);
    q.w = rne16(a6) | (rne16(a7) << 16);
    return q;
}
#define UNPK(q, p)                                                              \
    float p##0 = __uint_as_float((q).x << 16),                                  \
          p##1 = __uint_as_float((q).x & 0xFFFF0000u),                          \
          p##2 = __uint_as_float((q).y << 16),                                  \
          p##3 = __uint_as_float((q).y & 0xFFFF0000u),                          \
          p##4 = __uint_as_float((q).z << 16),                                  \
          p##5 = __uint_as_float((q).z & 0xFFFF0000u),                          \
          p##6 = __uint_as_float((q).w << 16),                                  \
          p##7 = __uint_as_float((q).w & 0xFFFF0000u)

// P_hat(x) = exp(softmax_val)/4 computed on the fly from raw bf16 logit x.
#define P1(x, km, ki)                                                           \
    __builtin_amdgcn_exp2f(fmaf(                                                \
        __builtin_amdgcn_exp2f(fmaf((x), INV_LN2F, -(km))) * (ki),              \
        INV_LN2F, -2.0f))

#define WROW(t) (*(const uint4*)(Wbb + (size_t)(t) * S_ + l8))
#define BROW(t) (*(const uint4*)(Btb + (size_t)(t) * S_ + l8))

// ---------------------------------------------------------------------------
// DPP helpers: VALU-only cross-lane.
template <int CTRL>
__device__ __forceinline__ float fdpp0(float x) {     // invalid src lanes -> 0
    return __uint_as_float((unsigned)__builtin_amdgcn_update_dpp(
        0, (int)__float_as_uint(x), CTRL, 0xF, 0xF, true));
}
__device__ __forceinline__ float wave_fmax(float x) { // uniform full-wave max
    x = fmaxf(x, fdpp0<0x121>(x));   // row_ror:1
    x = fmaxf(x, fdpp0<0x122>(x));   // row_ror:2
    x = fmaxf(x, fdpp0<0x124>(x));   // row_ror:4
    x = fmaxf(x, fdpp0<0x128>(x));   // row_ror:8
    float a = __uint_as_float((unsigned)__builtin_amdgcn_readlane((int)__float_as_uint(x), 0));
    float b = __uint_as_float((unsigned)__builtin_amdgcn_readlane((int)__float_as_uint(x), 16));
    float c = __uint_as_float((unsigned)__builtin_amdgcn_readlane((int)__float_as_uint(x), 32));
    float d = __uint_as_float((unsigned)__builtin_amdgcn_readlane((int)__float_as_uint(x), 48));
    return fmaxf(fmaxf(a, b), fmaxf(c, d));
}

__device__ __forceinline__ void gll16(const u16* g, u16* l) {
    __builtin_amdgcn_global_load_lds(
        (const __attribute__((address_space(1))) void*)g,
        (__attribute__((address_space(3))) void*)l, 16, 0, 0);
}
#define WAITV(N) do { asm volatile("s_waitcnt vmcnt(" #N ")" ::: "memory");     \
                      __builtin_amdgcn_sched_barrier(0); } while (0)
#define FENCE_LGKM() do { asm volatile("s_waitcnt lgkmcnt(0)" ::: "memory");    \
                          __builtin_amdgcn_sched_barrier(0); } while (0)

// ---------------------------------------------------------------------------
// K0: fused eps->bf16 + eps^2 partials (blocks 0..1535) and cond->bf16 (rest).
__global__ __launch_bounds__(256) void k_pre(const float* __restrict__ eps,
                                             const float* __restrict__ cond,
                                             const int* __restrict__ tlen,
                                             float* __restrict__ lp_part,
                                             u16* __restrict__ Abf,
                                             u16* __restrict__ Bbf) {
    if (blockIdx.x < 1536) {
        const int b = blockIdx.x / 48, chunk = blockIdx.x % 48;
        const int len = tlen[b];
        const float* base = eps + (size_t)b * T_ * C_ + (size_t)chunk * 8192;
        u16* obase = Abf + (size_t)b * T_ * C_ + (size_t)chunk * 8192;
        float acc = 0.f;
        for (int g = threadIdx.x; g < 1024; g += 256) {
            float4 v0 = *(const float4*)(base + g * 8);
            float4 v1 = *(const float4*)(base + g * 8 + 4);
            int t = (chunk * 8192 + g * 8) / C_;
            if (t < len)
                acc += v0.x*v0.x + v0.y*v0.y + v0.z*v0.z + v0.w*v0.w
                     + v1.x*v1.x + v1.y*v1.y + v1.z*v1.z + v1.w*v1.w;
            *(uint4*)(obase + g * 8) = pack8f(v0.x, v0.y, v0.z, v0.w,
                                              v1.x, v1.y, v1.z, v1.w);
        }
        __shared__ float red[256];
        red[threadIdx.x] = acc;
        __syncthreads();
        for (int o = 128; o > 0; o >>= 1) {
            if (threadIdx.x < o) red[threadIdx.x] += red[threadIdx.x + o];
            __syncthreads();
        }
        if (threadIdx.x == 0) lp_part[blockIdx.x] = -0.5f * red[0];
    } else {
        const size_t n8 = (size_t)B_ * S_ * C_ / 8;
        for (size_t i = (size_t)(blockIdx.x - 1536) * 256 + threadIdx.x; i < n8;
             i += (size_t)512 * 256) {
            float4 v0 = *(const float4*)(cond + i * 8);
            float4 v1 = *(const float4*)(cond + i * 8 + 4);
            *(uint4*)(Bbf + i * 8) = pack8f(v0.x, v0.y, v0.z, v0.w,
                                            v1.x, v1.y, v1.z, v1.w);
        }
    }
}

// ---------------------------------------------------------------------------
// K1: bf16 MFMA GEMM -> bf16 logits Wb + per-(b,64-t-chunk,s) softmax partials
// fused in the epilogue (deletes the separate stats pass over Wb).
__global__ __launch_bounds__(256) void k_gemm(const u16* __restrict__ A,
                                              const u16* __restrict__ Bc,
                                              u16* __restrict__ Wb,
                                              float* __restrict__ pmax,
                                              float* __restrict__ psum) {
    __shared__ u16 Al[4096];
    __shared__ u16 Bl[4096];
    const int wgid = blockIdx.x;
    const int xcd  = wgid & 7;
    const int rest = wgid >> 3;            // 0..127
    const int b    = (rest >> 5) * 8 + xcd;
    const int tile = rest & 31;            // 0..31 = (m,n) tile
    const int m0 = (tile >> 2) * 128;
    const int n0 = (tile & 3) * 128;
    const int tid = threadIdx.x;
    const int lane = tid & 63, wid = tid >> 6;
    const int wy = wid >> 1, wx = wid & 1;
    const int r15 = lane & 15, kg = lane >> 4;
    const u16* Ab = A  + (size_t)b * T_ * C_;
    const u16* Bb = Bc + (size_t)b * S_ * C_;

    f32x4 acc[4][4];
#pragma unroll
    for (int i = 0; i < 4; ++i)
#pragma unroll
        for (int j = 0; j < 4; ++j) acc[i][j] = (f32x4){0.f, 0.f, 0.f, 0.f};

    const int row0 = tid >> 2, o0 = tid & 3;
    const int row1 = row0 + 64;
    const int wb0 = (row0 * 64 + o0 * 16) ^ (((row0 >> 1) & 7) << 4);
    const int wb1 = (row1 * 64 + o0 * 16) ^ (((row1 >> 1) & 7) << 4);
    const int rswz = ((r15 >> 1) & 7) << 4;

    for (int k0 = 0; k0 < C_; k0 += 32) {
        uint4 a0 = *(const uint4*)(Ab + (size_t)(m0 + row0) * C_ + k0 + o0 * 8);
        uint4 a1 = *(const uint4*)(Ab + (size_t)(m0 + row1) * C_ + k0 + o0 * 8);
        uint4 c0 = *(const uint4*)(Bb + (size_t)(n0 + row0) * C_ + k0 + o0 * 8);
        uint4 c1 = *(const uint4*)(Bb + (size_t)(n0 + row1) * C_ + k0 + o0 * 8);
        __syncthreads();
        *(uint4*)((char*)Al + wb0) = a0;
        *(uint4*)((char*)Al + wb1) = a1;
        *(uint4*)((char*)Bl + wb0) = c0;
        *(uint4*)((char*)Bl + wb1) = c1;
        __syncthreads();
        bf16x8 af[4], bfb[4];
#pragma unroll
        for (int ar = 0; ar < 4; ++ar) {
            int row = wy * 64 + ar * 16 + r15;
            af[ar] = *(const bf16x8*)((const char*)Al + ((row * 64 + kg * 16) ^ rswz));
        }
#pragma unroll
        for (int bc = 0; bc < 4; ++bc) {
            int row = wx * 64 + bc * 16 + r15;
            bfb[bc] = *(const bf16x8*)((const char*)Bl + ((row * 64 + kg * 16) ^ rswz));
        }
#pragma unroll
        for (int ar = 0; ar < 4; ++ar)
#pragma unroll
            for (int bc = 0; bc < 4; ++bc)
                acc[ar][bc] = __builtin_amdgcn_mfma_f32_16x16x32_bf16(
                    af[ar], bfb[bc], acc[ar][bc], 0, 0, 0);
    }
    // C-write (bf16)
#pragma unroll
    for (int ar = 0; ar < 4; ++ar) {
        int t = m0 + wy * 64 + ar * 16 + kg * 4;
#pragma unroll
        for (int bc = 0; bc < 4; ++bc) {
            int s = n0 + wx * 64 + bc * 16 + r15;
            u16* dst = Wb + ((size_t)b * T_ + t) * S_ + s;
#pragma unroll
            for (int r = 0; r < 4; ++r) dst[(size_t)r * S_] = (u16)rne16(acc[ar][bc][r]);
        }
    }
    // fused column-stats partials over this wave's 64 t-rows
    float pm[4], ps[4];
#pragma unroll
    for (int bc = 0; bc < 4; ++bc) {
        float mx = -3.0e38f;
#pragma unroll
        for (int ar = 0; ar < 4; ++ar)
#pragma unroll
            for (int r = 0; r < 4; ++r) mx = fmaxf(mx, acc[ar][bc][r]);
        float s = 0.f;
#pragma unroll
        for (int ar = 0; ar < 4; ++ar)
#pragma unroll
            for (int r = 0; r < 4; ++r)
                s += __builtin_amdgcn_exp2f((acc[ar][bc][r] - mx) * INV_LN2F);
        pm[bc] = mx; ps[bc] = s;
    }
#pragma unroll
    for (int bc = 0; bc < 4; ++bc) {
        float m2 = __shfl_xor(pm[bc], 16), s2 = __shfl_xor(ps[bc], 16);
        float nm = fmaxf(pm[bc], m2);
        ps[bc] = ps[bc] * __builtin_amdgcn_exp2f((pm[bc] - nm) * INV_LN2F)
               + s2     * __builtin_amdgcn_exp2f((m2     - nm) * INV_LN2F);
        pm[bc] = nm;
        m2 = __shfl_xor(pm[bc], 32); s2 = __shfl_xor(ps[bc], 32);
        nm = fmaxf(pm[bc], m2);
        ps[bc] = ps[bc] * __builtin_amdgcn_exp2f((pm[bc] - nm) * INV_LN2F)
               + s2     * __builtin_amdgcn_exp2f((m2     - nm) * INV_LN2F);
        pm[bc] = nm;
    }
    if (kg == 0) {
        const int tc = (m0 >> 6) + wy;   // 0..15
#pragma unroll
        for (int bc = 0; bc < 4; ++bc) {
            int col = n0 + wx * 64 + bc * 16 + r15;
            pmax[((size_t)tc * B_ + b) * S_ + col] = pm[bc];
            psum[((size_t)tc * B_ + b) * S_ + col] = ps[bc];
        }
    }
}

// ---------------------------------------------------------------------------
// K2: combine 16 per-chunk partials -> cmax, cinv.
__global__ __launch_bounds__(256) void k_stats2(const float* __restrict__ pmax,
                                                const float* __restrict__ psum,
                                                float* __restrict__ cmax,
                                                float* __restrict__ cinv) {
    const size_t i = (size_t)blockIdx.x * 256 + threadIdx.x;   // 0..B*S-1
    const size_t BS = (size_t)B_ * S_;
    float m = -3.0e38f;
    for (int cc = 0; cc < 16; ++cc) m = fmaxf(m, pmax[cc * BS + i]);
    float s = 0.f;
    for (int cc = 0; cc < 16; ++cc)
        s += psum[cc * BS + i] *
             __builtin_amdgcn_exp2f((pmax[cc * BS + i] - m) * INV_LN2F);
    cmax[i] = m;
    cinv[i] = 1.0f / s;
}

// ---------------------------------------------------------------------------
// K4: backward DP, linear domain, P computed on the fly from bf16 logits.
// 32 chunks of 32 + 32-step warm-up, 2-deep LDS double-buffer, DPP shift.
#define RENORM_B() do {                                                         \
    float mx_ = wave_fmax(fmaxf(fmaxf(fmaxf(m0,m1),fmaxf(m2,m3)),               \
                                fmaxf(fmaxf(m4,m5),fmaxf(m6,m7))));             \
    int eb_ = (__float_as_int(mx_) >> 23) & 255;                                \
    float sc_ = (eb_ > 0) ? __int_as_float((254 - eb_) << 23) : 1.0f;           \
    m0*=sc_; m1*=sc_; m2*=sc_; m3*=sc_; m4*=sc_; m5*=sc_; m6*=sc_; m7*=sc_;     \
} while (0)

#define BSTEPD(tt, jj) do {                                                     \
    uint4 q_ = *(const uint4*)&Pl[buf][jj][l8];                                 \
    UNPK(q_, xr);                                                               \
    float eP0=P1(xr0,km0,ki0), eP1=P1(xr1,km1,ki1);                             \
    float eP2=P1(xr2,km2,ki2), eP3=P1(xr3,km3,ki3);                             \
    float eP4=P1(xr4,km4,ki4), eP5=P1(xr5,km5,ki5);                             \
    float eP6=P1(xr6,km6,ki6), eP7=P1(xr7,km7,ki7);                             \
    float z0=m0*eP0, z1=m1*eP1, z2=m2*eP2, z3=m3*eP3;                           \
    float z4=m4*eP4, z5=m5*eP5, z6=m6*eP6, z7=m7*eP7;                           \
    float rt = fdpp0<0x130>(z0);  /* lane l <- l+1, lane63 -> 0 */              \
    m0=z0+z1; m1=z1+z2; m2=z2+z3; m3=z3+z4;                                     \
    m4=z4+z5; m5=z5+z6; m6=z6+z7; m7=z7+rt;                                     \
    if ((tt) < w0 + 32) {                                                       \
        uint4 st;                                                               \
        asm("v_cvt_pk_bf16_f32 %0, %1, %2" : "=v"(st.x) : "v"(m0), "v"(m1));    \
        asm("v_cvt_pk_bf16_f32 %0, %1, %2" : "=v"(st.y) : "v"(m2), "v"(m3));    \
        asm("v_cvt_pk_bf16_f32 %0, %1, %2" : "=v"(st.z) : "v"(m4), "v"(m5));    \
        asm("v_cvt_pk_bf16_f32 %0, %1, %2" : "=v"(st.w) : "v"(m6), "v"(m7));    \
        *(uint4*)(Bb + (size_t)(tt) * S_ + l8) = st;                            \
    }                                                                           \
} while (0)

__global__ __launch_bounds__(64) void k_beta(const u16* __restrict__ Wb,
                                             const float* __restrict__ cmax,
                                             const float* __restrict__ cinv,
                                             u16* __restrict__ Bt) {
    __shared__ u16 Pl[2][8][S_];        // 16 KB (raw logit rows)
    const int l = threadIdx.x, l8 = l * 8;
    const int xcd = blockIdx.x & 7;
    const int idx = blockIdx.x >> 3;
    const int c = idx & 31;
    const int b = ((idx >> 5) << 3) + xcd;   // all chunks of b on one XCD
    const int w0 = c * 32;
    const u16* Pb = Wb + (size_t)b * T_ * S_;
    u16*      Bb = Bt + (size_t)b * T_ * S_;
    const float4 cA = *(const float4*)(cmax + (size_t)b * S_ + l8);
    const float4 cB = *(const float4*)(cmax + (size_t)b * S_ + l8 + 4);
    const float4 iA = *(const float4*)(cinv + (size_t)b * S_ + l8);
    const float4 iB = *(const float4*)(cinv + (size_t)b * S_ + l8 + 4);
    const float km0=cA.x*INV_LN2F, km1=cA.y*INV_LN2F, km2=cA.z*INV_LN2F, km3=cA.w*INV_LN2F;
    const float km4=cB.x*INV_LN2F, km5=cB.y*INV_LN2F, km6=cB.z*INV_LN2F, km7=cB.w*INV_LN2F;
    const float ki0=iA.x, ki1=iA.y, ki2=iA.z, ki3=iA.w;
    const float ki4=iB.x, ki5=iB.y, ki6=iB.z, ki7=iB.w;

    float m0, m1, m2, m3, m4, m5, m6, m7;
    int te = w0 + 63;
    if (te > 1023) te = 1023;
    if (te == 1023) {    // exact init (c == 30, 31)
        m0 = m1 = m2 = m3 = m4 = m5 = m6 = 0.f;
        m7 = (l == 63) ? 1.f : 0.f;
        if (1023 < w0 + 32) {   // c == 31 stores init row
            uint4 st;
            asm("v_cvt_pk_bf16_f32 %0, %1, %2" : "=v"(st.x) : "v"(m0), "v"(m1));
            asm("v_cvt_pk_bf16_f32 %0, %1, %2" : "=v"(st.y) : "v"(m2), "v"(m3));
            asm("v_cvt_pk_bf16_f32 %0, %1, %2" : "=v"(st.z) : "v"(m4), "v"(m5));
            asm("v_cvt_pk_bf16_f32 %0, %1, %2" : "=v"(st.w) : "v"(m6), "v"(m7));
            *(uint4*)(Bb + (size_t)1023 * S_ + l8) = st;
        }
    } else {
        m0 = m1 = m2 = m3 = m4 = m5 = m6 = m7 = 1.f;
    }
    const int cnt = te - w0;            // 63/31, == 7 mod 8
    const int ng = (cnt + 1) >> 3;      // 8/4
#pragma unroll
    for (int r = 0; r < 8; ++r)
        gll16(Pb + (size_t)(te - r) * S_ + l8, &Pl[0][r][0]);
#pragma unroll
    for (int r = 0; r < 8; ++r)
        gll16(Pb + (size_t)(te - 8 - r) * S_ + l8, &Pl[1][r][0]);
    int tt = te - 1;
    int buf = 0;
    for (int g = 0; g < ng - 1; ++g) {
        WAITV(8);
        BSTEPD(tt - 0, 0);  BSTEPD(tt - 1, 1);  BSTEPD(tt - 2, 2);  BSTEPD(tt - 3, 3);
        BSTEPD(tt - 4, 4);  BSTEPD(tt - 5, 5);  BSTEPD(tt - 6, 6);  BSTEPD(tt - 7, 7);
        RENORM_B();
        FENCE_LGKM();
        if (g + 2 < ng) {
            const int bs = te - 8 * (g + 2);
#pragma unroll
            for (int r = 0; r < 8; ++r)
                gll16(Pb + (size_t)(bs - r) * S_ + l8, &Pl[buf][r][0]);
        }
        __builtin_amdgcn_sched_barrier(0);
        buf ^= 1;
        tt -= 8;
    }
    WAITV(0);
    BSTEPD(tt - 0, 0);  BSTEPD(tt - 1, 1);  BSTEPD(tt - 2, 2);  BSTEPD(tt - 3, 3);
    BSTEPD(tt - 4, 4);  BSTEPD(tt - 5, 5);  BSTEPD(tt - 6, 6);
}

// ---------------------------------------------------------------------------
// K5: fused mu-forward + Viterbi, P on the fly, 32 chunks of 32, 32 warm-up,
// 2-deep LDS double-buffer on both streams.
#define RENORM_MI() do {                                                        \
    float mx_ = wave_fmax(fmaxf(fmaxf(fmaxf(m0,m1),fmaxf(m2,m3)),               \
                                fmaxf(fmaxf(m4,m5),fmaxf(m6,m7))));             \
    int eb_ = (__float_as_int(mx_) >> 23) & 255;                                \
    float sc_ = (eb_ > 0) ? __int_as_float((254 - eb_) << 23) : 1.0f;           \
    if (eb_ > 0) ioffM += eb_ - 127;                                            \
    m0*=sc_; m1*=sc_; m2*=sc_; m3*=sc_; m4*=sc_; m5*=sc_; m6*=sc_; m7*=sc_;     \
} while (0)

#define RENORM_VR() do {                                                        \
    float mx_ = wave_fmax(fmaxf(fmaxf(fmaxf(v0,v1),fmaxf(v2,v3)),               \
                                fmaxf(fmaxf(v4,v5),fmaxf(v6,v7))));             \
    int eb_ = (__float_as_int(mx_) >> 23) & 255;                                \
    float sc_ = (eb_ > 0) ? __int_as_float((254 - eb_) << 23) : 0.0f;           \
    float ad_ = (eb_ > 0) ? 0.f : 1.f;                                          \
    v0=fmaf(v0,sc_,ad_); v1=fmaf(v1,sc_,ad_); v2=fmaf(v2,sc_,ad_);              \
    v3=fmaf(v3,sc_,ad_); v4=fmaf(v4,sc_,ad_); v5=fmaf(v5,sc_,ad_);              \
    v6=fmaf(v6,sc_,ad_); v7=fmaf(v7,sc_,ad_);                                   \
} while (0)

#define VSTEPD(TT, jj) do {                                                     \
    uint4 qp_ = *(const uint4*)&Pl[buf][jj][l8];                                \
    uint4 qb_ = *(const uint4*)&Bl[buf][jj][l8];                                \
    UNPK(qp_, xr); UNPK(qb_, eB);                                               \
    float eP0=P1(xr0,km0,ki0), eP1=P1(xr1,km1,ki1);                             \
    float eP2=P1(xr2,km2,ki2), eP3=P1(xr3,km3,ki3);                             \
    float eP4=P1(xr4,km4,ki4), eP5=P1(xr5,km5,ki5);                             \
    float eP6=P1(xr6,km6,ki6), eP7=P1(xr7,km7,ki7);                             \
    float lf = fdpp0<0x138>(m7);  /* lane l <- l-1, lane0 -> 0 */               \
    float n0 = eP0*(m0+lf), n1 = eP1*(m1+m0);                                   \
    float n2 = eP2*(m2+m1), n3 = eP3*(m3+m2);                                   \
    float n4 = eP4*(m4+m3), n5 = eP5*(m5+m4);                                   \
    float n6 = eP6*(m6+m5), n7 = eP7*(m7+m6);                                   \
    float vlf = fdpp0<0x138>(v7);                                               \
    if ((TT) >= w0) {                                                           \
        unsigned cc0=(vlf>v0)?1u:0u, cc1=(v0>v1)?2u:0u, cc2=(v1>v2)?4u:0u,      \
                 cc3=(v2>v3)?8u:0u,  cc4=(v3>v4)?16u:0u, cc5=(v4>v5)?32u:0u,    \
                 cc6=(v5>v6)?64u:0u, cc7=(v6>v7)?128u:0u;                       \
        acc |= ((u64)(cc0|cc1|cc2|cc3|cc4|cc5|cc6|cc7)) << (((TT)&7)*8);        \
        if (((TT)&7) == 7) { mrow[((TT)>>3)*64 + l] = acc; acc = 0ULL; }        \
    }                                                                           \
    float w0v=(n0*eB0)*fmaxf(v0,vlf), w1v=(n1*eB1)*fmaxf(v1,v0);                \
    float w2v=(n2*eB2)*fmaxf(v2,v1),  w3v=(n3*eB3)*fmaxf(v3,v2);                \
    float w4v=(n4*eB4)*fmaxf(v4,v3),  w5v=(n5*eB5)*fmaxf(v5,v4);                \
    float w6v=(n6*eB6)*fmaxf(v6,v5),  w7v=(n7*eB7)*fmaxf(v7,v6);                \
    m0=n0;m1=n1;m2=n2;m3=n3;m4=n4;m5=n5;m6=n6;m7=n7;                            \
    v0=w0v;v1=w1v;v2=w2v;v3=w3v;v4=w4v;v5=w5v;v6=w6v;v7=w7v;                    \
    if ((TT) == wexp) { wex = __shfl(m0, 2 * c); wio = ioffM; }                 \
} while (0)

__global__ __launch_bounds__(64) void k_vit(const u16* __restrict__ Wb,
                                            const u16* __restrict__ Bt,
                                            const float* __restrict__ cmax,
                                            const float* __restrict__ cinv,
                                            u64* __restrict__ mbg,
                                            float* __restrict__ elog,
                                            float* __restrict__ wlg) {
    __shared__ u16 Pl[2][8][S_];        // 16 KB (raw logit rows)
    __shared__ u16 Bl[2][8][S_];        // 16 KB (beta rows)
    const int l = threadIdx.x, l8 = l * 8;
    const int xcd = blockIdx.x & 7;
    const int idx = blockIdx.x >> 3;
    const int c = idx & 31;
    const int b = ((idx >> 5) << 3) + xcd;
    const int w0 = c * 32, tend = w0 + 31;
    const int t0 = (w0 >= 32) ? (w0 - 32) : 0;
    const int wexp = w0 - 1;
    const u16* Wbb = Wb + (size_t)b * T_ * S_;
    const u16* Pb  = Wbb;
    const u16* Btb = Bt + (size_t)b * T_ * S_;
    u64* mrow = mbg + (size_t)b * 8192;
    const float4 cA = *(const float4*)(cmax + (size_t)b * S_ + l8);
    const float4 cB = *(const float4*)(cmax + (size_t)b * S_ + l8 + 4);
    const float4 iA = *(const float4*)(cinv + (size_t)b * S_ + l8);
    const float4 iB = *(const float4*)(cinv + (size_t)b * S_ + l8 + 4);
    const float km0=cA.x*INV_LN2F, km1=cA.y*INV_LN2F, km2=cA.z*INV_LN2F, km3=cA.w*INV_LN2F;
    const float km4=cB.x*INV_LN2F, km5=cB.y*INV_LN2F, km6=cB.z*INV_LN2F, km7=cB.w*INV_LN2F;
    const float ki0=iA.x, ki1=iA.y, ki2=iA.z, ki3=iA.w;
    const float ki4=iB.x, ki5=iB.y, ki6=iB.z, ki7=iB.w;

    float m0,m1,m2,m3,m4,m5,m6,m7, v0,v1,v2,v3,v4,v5,v6,v7;
    int ioffM = 0;
    float wex = 1.f; int wio = 0;
    {
        uint4 qp = WROW(t0); UNPK(qp, xr);
        uint4 qb = BROW(t0); UNPK(qb, eB);
        float p0i=P1(xr0,km0,ki0), p1i=P1(xr1,km1,ki1);
        float p2i=P1(xr2,km2,ki2), p3i=P1(xr3,km3,ki3);
        float p4i=P1(xr4,km4,ki4), p5i=P1(xr5,km5,ki5);
        float p6i=P1(xr6,km6,ki6), p7i=P1(xr7,km7,ki7);
        if (t0 == 0) {   // exact init (c == 0, 1)
            m0 = (l == 0) ? p0i : 0.f;
            m1 = 0.f; m2 = 0.f; m3 = 0.f; m4 = 0.f; m5 = 0.f; m6 = 0.f; m7 = 0.f;
        } else {
            m0 = p0i; m1 = p1i; m2 = p2i; m3 = p3i;
            m4 = p4i; m5 = p5i; m6 = p6i; m7 = p7i;
        }
        v0 = m0*eB0; v1 = m1*eB1; v2 = m2*eB2; v3 = m3*eB3;
        v4 = m4*eB4; v5 = m5*eB5; v6 = m6*eB6; v7 = m7*eB7;
    }
    u64 acc = 0ULL;
    const int cnt = tend - t0;          // 63/31
    const int ng = (cnt + 1) >> 3;      // 8/4
#pragma unroll
    for (int r = 0; r < 8; ++r) {
        gll16(Pb  + (size_t)(t0 + 1 + r) * S_ + l8, &Pl[0][r][0]);
        gll16(Btb + (size_t)(t0 + 1 + r) * S_ + l8, &Bl[0][r][0]);
    }
#pragma unroll
    for (int r = 0; r < 8; ++r) {
        gll16(Pb  + (size_t)(t0 + 9 + r) * S_ + l8, &Pl[1][r][0]);
        gll16(Btb + (size_t)(t0 + 9 + r) * S_ + l8, &Bl[1][r][0]);
    }
    int t = t0 + 1;
    int buf = 0;
    for (int g = 0; g < ng - 1; ++g) {
        WAITV(16);
        VSTEPD(t + 0, 0);  VSTEPD(t + 1, 1);  VSTEPD(t + 2, 2);  VSTEPD(t + 3, 3);
        VSTEPD(t + 4, 4);  VSTEPD(t + 5, 5);  VSTEPD(t + 6, 6);  VSTEPD(t + 7, 7);
        RENORM_MI();
        RENORM_VR();
        FENCE_LGKM();
        if (g + 2 < ng) {
            const int bs = t0 + 1 + 8 * (g + 2);
#pragma unroll
            for (int r = 0; r < 8; ++r) {
                gll16(Pb  + (size_t)(bs + r) * S_ + l8, &Pl[buf][r][0]);
                gll16(Btb + (size_t)(bs + r) * S_ + l8, &Bl[buf][r][0]);
            }
        }
        __builtin_amdgcn_sched_barrier(0);
        buf ^= 1;
        t += 8;
    }
    WAITV(0);
    VSTEPD(t + 0, 0);  VSTEPD(t + 1, 1);  VSTEPD(t + 2, 2);  VSTEPD(t + 3, 3);
    VSTEPD(t + 4, 4);  VSTEPD(t + 5, 5);  VSTEPD(t + 6, 6);

    float eex = (c == 31) ? __shfl(m7, 63) : __shfl(m0, 2 * (c + 1));
    if (l == 0) {
        elog[b * 32 + c] = __builtin_amdgcn_logf(fmaxf(eex, 1e-35f)) + (float)ioffM;
        if (c >= 1)
            wlg[b * 32 + c] = __builtin_amdgcn_logf(fmaxf(wex, 1e-35f)) + (float)wio;
    }
}

// ---------------------------------------------------------------------------
// K6a: per-(b,chunk) backtrace maps.
__global__ __launch_bounds__(512) void k_map(const u64* __restrict__ mbg,
                                             u16* __restrict__ map) {
    __shared__ u64 mb[4][64];   // 2 KB: taus 4c..4c+3
    const int b = blockIdx.x >> 5, c = blockIdx.x & 31;
    const int tid = threadIdx.x;
    const u64* src = mbg + (size_t)b * 8192 + (size_t)(4 * c) * 64;
    if (tid < 128) ((uint4*)&mb[0][0])[tid] = ((const uint4*)src)[tid];
    __syncthreads();
    int jj = tid;
    const int kmin = (c == 0) ? 1 : 0;
    for (int k = 31; k >= kmin; --k) {
        u64 word = mb[k >> 3][jj >> 3];
        jj -= (int)((word >> ((k & 7) * 8 + (jj & 7))) & 1ULL);
    }
    map[((size_t)b * 32 + c) * 512 + tid] = (u16)jj;
}

// K6b: compose maps then 32 lanes re-trace chunks in parallel.
__global__ __launch_bounds__(256) void k_btr2(const u64* __restrict__ mbg,
                                              const u16* __restrict__ map,
                                              int* __restrict__ js) {
    __shared__ u64 mb[128][64];   // 64 KB
    __shared__ u16 cent[32];
    const int b = blockIdx.x, tid = threadIdx.x;
    const uint4* src = (const uint4*)(mbg + (size_t)b * 8192);
    uint4* dst = (uint4*)&mb[0][0];
    for (int i = tid; i < 4096; i += 256) dst[i] = src[i];
    if (tid == 0) {
        int jj = 511;
        cent[31] = 511;
        for (int c = 31; c >= 1; --c) {
            jj = (int)map[((size_t)b * 32 + c) * 512 + jj];
            cent[c - 1] = (u16)jj;
        }
    }
    __syncthreads();
    if (tid < 32) {
        const int c = tid;
        int jj = (int)cent[c];
        js[b * T_ + 32 * c + 31] = jj;
        const int kmin = (c == 0) ? 1 : 0;
        for (int k = 31; k >= kmin; --k) {
            const int t = 32 * c + k;
            u64 word = mb[t >> 3][jj >> 3];
            jj -= (int)((word >> ((t & 7) * 8 + (jj & 7))) & 1ULL);
            js[b * T_ + t - 1] = jj;
        }
    }
}

// ---------------------------------------------------------------------------
// K7: fused one-hot path writer (blocks 0..4095) + logprobs (blocks 4096..4127).
__global__ __launch_bounds__(256) void k_out(const int* __restrict__ js,
                                             const u16* __restrict__ Wb,
                                             const float* __restrict__ cmax,
                                             const float* __restrict__ cinv,
                                             const float* __restrict__ lp_part,
                                             const int* __restrict__ tlen,
                                             const float* __restrict__ elog,
                                             const float* __restrict__ wlg,
                                             float* __restrict__ outp,
                                             float* __restrict__ out_lp) {
    if (blockIdx.x < 4096) {
        const size_t total4 = (size_t)B_ * T_ * S_ / 4;
        float4* O = (float4*)outp;
        for (size_t i = (size_t)blockIdx.x * 256 + threadIdx.x; i < total4;
             i += (size_t)4096 * 256) {
            size_t base = i * 4;
            int s = (int)(base & (S_ - 1));
            int row = (int)(base >> 9);
            int jt = js[row];
            float4 o;
            o.x = (s == jt) ? 1.f : 0.f;
            o.y = (s + 1 == jt) ? 1.f : 0.f;
            o.z = (s + 2 == jt) ? 1.f : 0.f;
            o.w = (s + 3 == jt) ? 1.f : 0.f;
            O[i] = o;
        }
    } else {
        const int b = blockIdx.x - 4096;
        float acc = 0.f;   // sum of log2(P_hat) along the path
        for (int t = threadIdx.x; t < T_; t += 256) {
            int jt = js[b * T_ + t];
            float x = __uint_as_float(
                (unsigned)Wb[((size_t)b * T_ + t) * S_ + jt] << 16);
            float cm = cmax[(size_t)b * S_ + jt];
            float ci = cinv[(size_t)b * S_ + jt];
            float w = __builtin_amdgcn_exp2f(fmaf(x, INV_LN2F, -cm * INV_LN2F)) * ci;
            acc += fmaf(w, INV_LN2F, -2.0f);
        }
        __shared__ float red[256];
        red[threadIdx.x] = acc;
        __syncthreads();
        for (int o = 128; o > 0; o >>= 1) {
            if (threadIdx.x < o) red[threadIdx.x] += red[threadIdx.x + o];
            __syncthreads();
        }
        if (threadIdx.x == 0) {
            float basep = 0.f;
            for (int i = 0; i < 48; ++i) basep += lp_part[b * 48 + i];
            float mu2n = elog[b * 32 + 31];
            for (int cc = 1; cc < 32; ++cc)
                mu2n += elog[b * 32 + cc - 1] - wlg[b * 32 + cc];
            out_lp[b] = basep - HALF_LOG_2PI * ((float)tlen[b] * C_)
                        + LN2F * (red[0] - mu2n);
        }
    }
}

// ---------------------------------------------------------------------------
extern "C" void kernel_launch(void* const* d_in, const int* in_sizes, int n_in,
                              void* d_out, int out_size, void* d_ws, size_t ws_size,
                              hipStream_t stream) {
    const float* eps  = (const float*)d_in[0];
    const float* cond = (const float*)d_in[1];
    const int* tlen   = (const int*)d_in[2];

    float* out_path = (float*)d_out;
    float* out_lp   = out_path + (size_t)B_ * T_ * S_;

    const size_t NBTS = (size_t)B_ * T_ * S_;
    char* w = (char*)d_ws;
    u16*   Wb   = (u16*)w;                            // 34 MB bf16 logits
    u16*   Bt   = Wb + NBTS;                          // 34 MB bf16 linear beta
    u16*   Abf  = Bt + NBTS;                          // 25 MB bf16 eps
    u16*   Bbf  = Abf + (size_t)B_ * T_ * C_;         // 13 MB bf16 cond
    u64*   mbg  = (u64*)(Bbf + (size_t)B_ * S_ * C_); // 2 MB move bits
    float* pmax = (float*)(mbg + (size_t)B_ * 8192);  // 16*B*S = 1 MB
    float* psum = pmax + (size_t)16 * B_ * S_;        // 1 MB
    float* cmax = psum + (size_t)16 * B_ * S_;
    float* cinv = cmax + (size_t)B_ * S_;
    float* lp_part = cinv + (size_t)B_ * S_;
    float* elog = lp_part + B_ * 48;                  // B*32
    float* wlg  = elog + B_ * 32;                     // B*32
    int*   js   = (int*)(wlg + B_ * 32);              // B*T
    u16*   map  = (u16*)(js + B_ * T_);               // 1 MB backtrace maps

    k_pre<<<2048, 256, 0, stream>>>(eps, cond, tlen, lp_part, Abf, Bbf);
    k_gemm<<<1024, 256, 0, stream>>>(Abf, Bbf, Wb, pmax, psum);
    k_stats2<<<B_ * S_ / 256, 256, 0, stream>>>(pmax, psum, cmax, cinv);
    k_beta<<<B_ * 32, 64, 0, stream>>>(Wb, cmax, cinv, Bt);
    k_vit<<<B_ * 32, 64, 0, stream>>>(Wb, Bt, cmax, cinv, mbg, elog, wlg);
    k_map<<<B_ * 32, 512, 0, stream>>>(mbg, map);
    k_btr2<<<B_, 256, 0, stream>>>(mbg, map, js);
    k_out<<<4096 + B_, 256, 0, stream>>>(js, Wb, cmax, cinv, lp_part, tlen,
                                         elog, wlg, out_path, out_lp);
}